// Round 18
// baseline (576.292 us; speedup 1.0000x reference)
//
#include <hip/hip_runtime.h>
#include <cstddef>

using u16 = unsigned short;
using u32 = unsigned int;
typedef short bf16x8 __attribute__((ext_vector_type(8)));
typedef float f32x4 __attribute__((ext_vector_type(4)));

// ---------- bf16 helpers ----------
__device__ __forceinline__ u16 f2bf(float f) {
  u32 x = __float_as_uint(f);
  return (u16)((x + 0x7fffu + ((x >> 16) & 1u)) >> 16);  // RNE
}
__device__ __forceinline__ uint4 pack8(const float* f) {
  uint4 r;
  r.x = ((u32)f2bf(f[0])) | (((u32)f2bf(f[1])) << 16);
  r.y = ((u32)f2bf(f[2])) | (((u32)f2bf(f[3])) << 16);
  r.z = ((u32)f2bf(f[4])) | (((u32)f2bf(f[5])) << 16);
  r.w = ((u32)f2bf(f[6])) | (((u32)f2bf(f[7])) << 16);
  return r;
}
__device__ __forceinline__ float fast_exp2(float x) {
  float r; asm("v_exp_f32 %0, %1" : "=v"(r) : "v"(x)); return r;
}
__device__ __forceinline__ float gelu_f(float x) {
  const float u = x * (0.7978845608f + 0.0356774081f * x * x);
  const float e = fast_exp2(u * 2.8853900818f);  // exp(2u)
  const float t = 1.f - 2.f / (e + 1.f);
  return 0.5f * x * (1.f + t);
}
__device__ __forceinline__ void gload16(const void* g, void* l) {
  __builtin_amdgcn_global_load_lds(
      (const __attribute__((address_space(1))) u32*)g,
      (__attribute__((address_space(3))) u32*)l, 16, 0, 0);
}

// ---------- MFMA GEMM (M%128==0), BK=64: C = epi(A[M,K] @ Wt[N,K]^T + bias) ----------
__global__ __launch_bounds__(256, 3) void gemm_mfma_g(
    const u16* __restrict__ A, const u16* __restrict__ Wt,
    const float* __restrict__ bias, void* __restrict__ Cout,
    int M, int N, int K, int outmode, int swz)
{
  __shared__ u16 As[128 * 64];
  __shared__ u16 Bs[128 * 64];
  const int tid = threadIdx.x;
  const int wave = tid >> 6, lane = tid & 63;
  const int wr = wave >> 1, wc = wave & 1;

  int xt, yt;
  if (swz) {
    const int lin = blockIdx.y * gridDim.x + blockIdx.x;
    const int k = lin & 7, j = lin >> 3;
    const int xw = gridDim.x;
    yt = 8 * k + j / xw;
    xt = j - (j / xw) * xw;
  } else {
    xt = blockIdx.x; yt = blockIdx.y;
  }
  const int m0 = yt * 128, n0 = xt * 128;
  const int lrow = lane & 15, lk = lane >> 4;

  const int rr = lane >> 3;        // 0..7
  const int cb = (lane & 7) * 16;  // byte col 0..112

  f32x4 acc[4][4];
#pragma unroll
  for (int i = 0; i < 4; ++i)
#pragma unroll
    for (int j = 0; j < 4; ++j) {
      acc[i][j][0] = 0.f; acc[i][j][1] = 0.f; acc[i][j][2] = 0.f; acc[i][j][3] = 0.f;
    }

  for (int k0 = 0; k0 < K; k0 += 64) {
    __syncthreads();
#pragma unroll
    for (int i = 0; i < 4; ++i) {
      const int Rloc = wave * 32 + i * 8 + rr;
      const int scb = cb ^ ((Rloc & 7) << 4);
      gload16(A + (size_t)(m0 + Rloc) * K + k0 + (scb >> 1),
              &As[(wave * 32 + i * 8) * 64]);
      gload16(Wt + (size_t)(n0 + Rloc) * K + k0 + (scb >> 1),
              &Bs[(wave * 32 + i * 8) * 64]);
    }
    __syncthreads();

#pragma unroll
    for (int kk = 0; kk < 2; ++kk) {
      bf16x8 af[4], bf[4];
#pragma unroll
      for (int i = 0; i < 4; ++i) {
        const int rA = wr * 64 + i * 16 + lrow;
        af[i] = *(const bf16x8*)&As[rA * 64 + (((kk * 64 + lk * 16) ^ ((rA & 7) << 4)) >> 1)];
        const int rB = wc * 64 + i * 16 + lrow;
        bf[i] = *(const bf16x8*)&Bs[rB * 64 + (((kk * 64 + lk * 16) ^ ((rB & 7) << 4)) >> 1)];
      }
#pragma unroll
      for (int i = 0; i < 4; ++i)
#pragma unroll
        for (int j = 0; j < 4; ++j)
          acc[i][j] = __builtin_amdgcn_mfma_f32_16x16x32_bf16(af[i], bf[j], acc[i][j], 0, 0, 0);
    }
  }

#pragma unroll
  for (int j = 0; j < 4; ++j) {
    const int gcol = n0 + wc * 64 + j * 16 + lrow;
    const float bj = bias[gcol];
#pragma unroll
    for (int i = 0; i < 4; ++i) {
      const int rbase = m0 + wr * 64 + i * 16 + lk * 4;
#pragma unroll
      for (int reg = 0; reg < 4; ++reg) {
        float c = acc[i][j][reg] + bj;
        if (outmode == 1) c = gelu_f(c);
        if (outmode == 2)
          ((float*)Cout)[(size_t)(rbase + reg) * N + gcol] = c;
        else
          ((u16*)Cout)[(size_t)(rbase + reg) * N + gcol] = f2bf(c);
      }
    }
  }
}

// ---------- MFMA GEMM, guarded (small M, e.g. tags M=50) ----------
__global__ __launch_bounds__(256, 2) void gemm_mfma_k(
    const u16* __restrict__ A, const u16* __restrict__ Wt,
    const float* __restrict__ bias, void* __restrict__ Cout,
    int M, int N, int K, int outmode)
{
  __shared__ u16 As[128][40];
  __shared__ u16 Bs[128][40];
  const int tid = threadIdx.x;
  const int wave = tid >> 6, lane = tid & 63;
  const int wr = wave >> 1, wc = wave & 1;
  const int m0 = blockIdx.y * 128, n0 = blockIdx.x * 128;
  const int lrow = lane & 15, lk = lane >> 4;

  f32x4 acc[4][4];
#pragma unroll
  for (int i = 0; i < 4; ++i)
#pragma unroll
    for (int j = 0; j < 4; ++j) {
      acc[i][j][0] = 0.f; acc[i][j][1] = 0.f; acc[i][j][2] = 0.f; acc[i][j][3] = 0.f;
    }

  const int sr = tid >> 2;
  const int sk = (tid & 3) * 8;
  const bool arow_ok0 = (m0 + sr) < M;
  const bool arow_ok1 = (m0 + sr + 64) < M;

  for (int k0 = 0; k0 < K; k0 += 32) {
    __syncthreads();
    if (arow_ok0)
      *(uint4*)&As[sr][sk] = *(const uint4*)&A[(size_t)(m0 + sr) * K + k0 + sk];
    if (arow_ok1)
      *(uint4*)&As[sr + 64][sk] = *(const uint4*)&A[(size_t)(m0 + sr + 64) * K + k0 + sk];
    *(uint4*)&Bs[sr][sk] = *(const uint4*)&Wt[(size_t)(n0 + sr) * K + k0 + sk];
    *(uint4*)&Bs[sr + 64][sk] = *(const uint4*)&Wt[(size_t)(n0 + sr + 64) * K + k0 + sk];
    __syncthreads();

    bf16x8 af[4], bf[4];
#pragma unroll
    for (int i = 0; i < 4; ++i) {
      af[i] = *(const bf16x8*)&As[wr * 64 + i * 16 + lrow][lk * 8];
      bf[i] = *(const bf16x8*)&Bs[wc * 64 + i * 16 + lrow][lk * 8];
    }
#pragma unroll
    for (int i = 0; i < 4; ++i)
#pragma unroll
      for (int j = 0; j < 4; ++j)
        acc[i][j] = __builtin_amdgcn_mfma_f32_16x16x32_bf16(af[i], bf[j], acc[i][j], 0, 0, 0);
  }

#pragma unroll
  for (int j = 0; j < 4; ++j) {
    const int gcol = n0 + wc * 64 + j * 16 + lrow;
    const float bj = bias[gcol];
#pragma unroll
    for (int i = 0; i < 4; ++i) {
      const int rbase = m0 + wr * 64 + i * 16 + lk * 4;
#pragma unroll
      for (int reg = 0; reg < 4; ++reg) {
        const int grow = rbase + reg;
        if (grow >= M) continue;
        float c = acc[i][j][reg] + bj;
        if (outmode == 1) c = gelu_f(c);
        if (outmode == 2)
          ((float*)Cout)[(size_t)grow * N + gcol] = c;
        else
          ((u16*)Cout)[(size_t)grow * N + gcol] = f2bf(c);
      }
    }
  }
}

// ---------- weight transpose+convert (single) ----------
__global__ __launch_bounds__(256) void transpose_conv(
    const float* __restrict__ W, u16* __restrict__ Wt, int K, int N)
{
  __shared__ float t[32][33];
  const int kb = blockIdx.y * 32, nb = blockIdx.x * 32;
  const int x = threadIdx.x & 31;
  const int y4 = (threadIdx.x >> 5) * 4;
#pragma unroll
  for (int i = 0; i < 4; ++i)
    t[y4 + i][x] = W[(size_t)(kb + y4 + i) * N + nb + x];
  __syncthreads();
#pragma unroll
  for (int i = 0; i < 4; ++i)
    Wt[(size_t)(nb + y4 + i) * K + kb + x] = f2bf(t[x][y4 + i]);
}

// ---------- batched 1024x1024 weight transpose+convert (8 matrices) ----------
__global__ __launch_bounds__(256) void transpose_conv8(
    const float* w0, const float* w1, const float* w2, const float* w3,
    const float* w4, const float* w5, const float* w6, const float* w7,
    u16* t0, u16* t1, u16* t2, u16* t3,
    u16* t4, u16* t5, u16* t6, u16* t7)
{
  const int K = 1024, N = 1024;
  const float* W; u16* Wt;
  switch (blockIdx.z) {
    case 0: W = w0; Wt = t0; break;
    case 1: W = w1; Wt = t1; break;
    case 2: W = w2; Wt = t2; break;
    case 3: W = w3; Wt = t3; break;
    case 4: W = w4; Wt = t4; break;
    case 5: W = w5; Wt = t5; break;
    case 6: W = w6; Wt = t6; break;
    default: W = w7; Wt = t7; break;
  }
  __shared__ float t[32][33];
  const int kb = blockIdx.y * 32, nb = blockIdx.x * 32;
  const int x = threadIdx.x & 31;
  const int y4 = (threadIdx.x >> 5) * 4;
#pragma unroll
  for (int i = 0; i < 4; ++i)
    t[y4 + i][x] = W[(size_t)(kb + y4 + i) * N + nb + x];
  __syncthreads();
#pragma unroll
  for (int i = 0; i < 4; ++i)
    Wt[(size_t)(nb + y4 + i) * K + kb + x] = f2bf(t[x][y4 + i]);
}

// ---------- elementwise fp32 -> bf16 ----------
__global__ __launch_bounds__(256) void conv_bf16(
    const float* __restrict__ in, u16* __restrict__ out, int n4)
{
  const int idx = blockIdx.x * 256 + threadIdx.x;
  if (idx >= n4) return;
  const float4 v = reinterpret_cast<const float4*>(in)[idx];
  const float f[4] = {v.x, v.y, v.z, v.w};
  uint2 pk;
  pk.x = ((u32)f2bf(f[0])) | (((u32)f2bf(f[1])) << 16);
  pk.y = ((u32)f2bf(f[2])) | (((u32)f2bf(f[3])) << 16);
  reinterpret_cast<uint2*>(out)[idx] = pk;
}

// ---------- bias packing: bqkv[3072] = {sqb,skb,svb}; bckv[2048] = {ckb,cvb} ----------
__global__ __launch_bounds__(256) void pack_bias(
    const float* __restrict__ sqb, const float* __restrict__ skb,
    const float* __restrict__ svb, const float* __restrict__ ckb,
    const float* __restrict__ cvb, float* __restrict__ bqkv,
    float* __restrict__ bckv)
{
  const int t = threadIdx.x;
  switch (blockIdx.x) {
    case 0: ((float4*)bqkv)[t] = ((const float4*)sqb)[t]; break;
    case 1: ((float4*)(bqkv + 1024))[t] = ((const float4*)skb)[t]; break;
    case 2: ((float4*)(bqkv + 2048))[t] = ((const float4*)svb)[t]; break;
    case 3: ((float4*)bckv)[t] = ((const float4*)ckb)[t]; break;
    default: ((float4*)(bckv + 1024))[t] = ((const float4*)cvb)[t]; break;
  }
}

// ---------- MFMA flash self-attention (packed QKV[M][3072]) ----------
__global__ __launch_bounds__(256, 4) void attn_self_mfma(
    const u16* __restrict__ QKV, u16* __restrict__ CTX,
    const int* __restrict__ rngp)
{
  const int S = 2048, H = 1024, SD = 3072;
  const float SC = 0.125f * 1.44269504f;
  const float MB = 1.44269504f;
  const int qt = blockIdx.x, h = blockIdx.y, b = blockIdx.z;
  const int range = rngp[0];
  const int tid = threadIdx.x;
  const int wave = tid >> 6, lane = tid & 63;
  const int lcol = lane & 15;
  const int lgrp = lane >> 4;

  __shared__ u16 Vt[64][72];
  __shared__ u16 Pb[4][32][72];

  const int qbase = qt * 128 + wave * 32;
  const u16* Kp = QKV + 1024;
  const u16* Vp = QKV + 2048;

  bf16x8 qf[2][2];
#pragma unroll
  for (int rf = 0; rf < 2; ++rf)
#pragma unroll
    for (int dh = 0; dh < 2; ++dh) {
      const int qrow = qbase + rf * 16 + lcol;
      qf[rf][dh] = *(const bf16x8*)&QKV[((size_t)(b * S + qrow)) * SD + h * 64 + dh * 32 + lgrp * 8];
    }

  f32x4 acc[2][4];
#pragma unroll
  for (int rf = 0; rf < 2; ++rf)
#pragma unroll
    for (int df = 0; df < 4; ++df) {
      acc[rf][df][0] = 0.f; acc[rf][df][1] = 0.f; acc[rf][df][2] = 0.f; acc[rf][df][3] = 0.f;
    }
  float lreg[2][4];
#pragma unroll
  for (int rf = 0; rf < 2; ++rf)
#pragma unroll
    for (int reg = 0; reg < 4; ++reg) lreg[rf][reg] = 0.f;

  for (int c = 0; c < 32; ++c) {
    const int kb = c * 64;
    __syncthreads();
    {
      const u16* vsrc = &Vp[((size_t)(b * S + kb + lane)) * SD + h * 64 + wave * 16];
      uint4 u0 = *(const uint4*)vsrc;
      uint4 u1 = *(const uint4*)(vsrc + 8);
      u16 tmp[16];
      *(uint4*)tmp = u0; *(uint4*)(tmp + 8) = u1;
#pragma unroll
      for (int i = 0; i < 16; ++i) Vt[wave * 16 + i][lane] = tmp[i];
    }
    f32x4 s[2][4];
#pragma unroll
    for (int rf = 0; rf < 2; ++rf)
#pragma unroll
      for (int cf = 0; cf < 4; ++cf) {
        s[rf][cf][0] = 0.f; s[rf][cf][1] = 0.f; s[rf][cf][2] = 0.f; s[rf][cf][3] = 0.f;
      }
#pragma unroll
    for (int dh = 0; dh < 2; ++dh)
#pragma unroll
      for (int cf = 0; cf < 4; ++cf) {
        const int krow = kb + cf * 16 + lcol;
        const bf16x8 kf = *(const bf16x8*)&Kp[((size_t)(b * S + krow)) * SD + h * 64 + dh * 32 + lgrp * 8];
#pragma unroll
        for (int rf = 0; rf < 2; ++rf)
          s[rf][cf] = __builtin_amdgcn_mfma_f32_16x16x32_bf16(qf[rf][dh], kf, s[rf][cf], 0, 0, 0);
      }
#pragma unroll
    for (int rf = 0; rf < 2; ++rf) {
#pragma unroll
      for (int reg = 0; reg < 4; ++reg) {
        const int qrow = qbase + rf * 16 + lgrp * 4 + reg;
#pragma unroll
        for (int cf = 0; cf < 4; ++cf) {
          const int kcol = kb + cf * 16 + lcol;
          int dd = qrow - kcol; if (dd < 0) dd = -dd;
          const float e = fast_exp2(s[rf][cf][reg] * SC + ((dd <= range) ? MB : 0.0f));
          s[rf][cf][reg] = e;
          lreg[rf][reg] += e;
        }
      }
    }
#pragma unroll
    for (int rf = 0; rf < 2; ++rf)
#pragma unroll
      for (int reg = 0; reg < 4; ++reg)
#pragma unroll
        for (int cf = 0; cf < 4; ++cf)
          Pb[wave][rf * 16 + lgrp * 4 + reg][cf * 16 + lcol] =
              (u16)(__float_as_uint(s[rf][cf][reg]) >> 16);
    __syncthreads();
#pragma unroll
    for (int ks = 0; ks < 2; ++ks) {
      bf16x8 pa[2], vb[4];
#pragma unroll
      for (int rf = 0; rf < 2; ++rf)
        pa[rf] = *(const bf16x8*)&Pb[wave][rf * 16 + lcol][ks * 32 + lgrp * 8];
#pragma unroll
      for (int df = 0; df < 4; ++df)
        vb[df] = *(const bf16x8*)&Vt[df * 16 + lcol][ks * 32 + lgrp * 8];
#pragma unroll
      for (int rf = 0; rf < 2; ++rf)
#pragma unroll
        for (int df = 0; df < 4; ++df)
          acc[rf][df] = __builtin_amdgcn_mfma_f32_16x16x32_bf16(pa[rf], vb[df], acc[rf][df], 0, 0, 0);
    }
  }
#pragma unroll
  for (int rf = 0; rf < 2; ++rf)
#pragma unroll
    for (int reg = 0; reg < 4; ++reg) {
      float l = lreg[rf][reg];
      l += __shfl_xor(l, 1);
      l += __shfl_xor(l, 2);
      l += __shfl_xor(l, 4);
      l += __shfl_xor(l, 8);
      lreg[rf][reg] = l;
    }
#pragma unroll
  for (int rf = 0; rf < 2; ++rf)
#pragma unroll
    for (int reg = 0; reg < 4; ++reg) {
      const int qrow = qbase + rf * 16 + lgrp * 4 + reg;
      const float inv = 1.f / lreg[rf][reg];
#pragma unroll
      for (int df = 0; df < 4; ++df)
        CTX[((size_t)(b * S + qrow)) * H + h * 64 + df * 16 + lcol] =
            f2bf(acc[rf][df][reg] * inv);
    }
}

// ---------- MFMA cross-attention: packed KV[50][2048] (K at 0, V at +1024) ----------
__global__ __launch_bounds__(256, 4) void attn_cross_mfma(
    const u16* __restrict__ Q, const u16* __restrict__ KV,
    u16* __restrict__ CTX)
{
  const int S = 2048, H = 1024, T = 50, KD = 2048;
  const float SC = 0.125f * 1.44269504f;
  const int qt = blockIdx.x, h = blockIdx.y, b = blockIdx.z;
  const int tid = threadIdx.x;
  const int wave = tid >> 6, lane = tid & 63;
  const int lcol = lane & 15;
  const int lgrp = lane >> 4;

  __shared__ u16 Vt[64][72];
  __shared__ u16 Pb[4][32][72];

  const int qbase = qt * 128 + wave * 32;

  bf16x8 qf[2][2];
#pragma unroll
  for (int rf = 0; rf < 2; ++rf)
#pragma unroll
    for (int dh = 0; dh < 2; ++dh) {
      const int qrow = qbase + rf * 16 + lcol;
      qf[rf][dh] = *(const bf16x8*)&Q[((size_t)(b * S + qrow)) * H + h * 64 + dh * 32 + lgrp * 8];
    }

  {
    u16 tmp[16];
    if (lane < T) {
      const u16* vsrc = &KV[(size_t)lane * KD + 1024 + h * 64 + wave * 16];
      *(uint4*)tmp = *(const uint4*)vsrc;
      *(uint4*)(tmp + 8) = *(const uint4*)(vsrc + 8);
    } else {
#pragma unroll
      for (int i = 0; i < 16; ++i) tmp[i] = 0;
    }
#pragma unroll
    for (int i = 0; i < 16; ++i) Vt[wave * 16 + i][lane] = tmp[i];
  }

  f32x4 s[2][4];
#pragma unroll
  for (int rf = 0; rf < 2; ++rf)
#pragma unroll
    for (int cf = 0; cf < 4; ++cf) {
      s[rf][cf][0] = 0.f; s[rf][cf][1] = 0.f; s[rf][cf][2] = 0.f; s[rf][cf][3] = 0.f;
    }
#pragma unroll
  for (int dh = 0; dh < 2; ++dh)
#pragma unroll
    for (int cf = 0; cf < 4; ++cf) {
      const int krow = cf * 16 + lcol;
      const bf16x8 kf = *(const bf16x8*)&KV[(size_t)krow * KD + h * 64 + dh * 32 + lgrp * 8];
#pragma unroll
      for (int rf = 0; rf < 2; ++rf)
        s[rf][cf] = __builtin_amdgcn_mfma_f32_16x16x32_bf16(qf[rf][dh], kf, s[rf][cf], 0, 0, 0);
    }

  float inv_l[2][4];
#pragma unroll
  for (int rf = 0; rf < 2; ++rf) {
#pragma unroll
    for (int reg = 0; reg < 4; ++reg) {
      float rmax = -1e30f;
#pragma unroll
      for (int cf = 0; cf < 4; ++cf) {
        const int kcol = cf * 16 + lcol;
        const float v = (kcol < T) ? s[rf][cf][reg] * SC : -1e30f;
        s[rf][cf][reg] = v;
        rmax = fmaxf(rmax, v);
      }
      rmax = fmaxf(rmax, __shfl_xor(rmax, 1));
      rmax = fmaxf(rmax, __shfl_xor(rmax, 2));
      rmax = fmaxf(rmax, __shfl_xor(rmax, 4));
      rmax = fmaxf(rmax, __shfl_xor(rmax, 8));
      float rsum = 0.f;
#pragma unroll
      for (int cf = 0; cf < 4; ++cf) {
        const float e = fast_exp2(s[rf][cf][reg] - rmax);
        s[rf][cf][reg] = e;
        rsum += e;
      }
      rsum += __shfl_xor(rsum, 1);
      rsum += __shfl_xor(rsum, 2);
      rsum += __shfl_xor(rsum, 4);
      rsum += __shfl_xor(rsum, 8);
      inv_l[rf][reg] = 1.f / rsum;
    }
  }
#pragma unroll
  for (int rf = 0; rf < 2; ++rf)
#pragma unroll
    for (int reg = 0; reg < 4; ++reg)
#pragma unroll
      for (int cf = 0; cf < 4; ++cf)
        Pb[wave][rf * 16 + lgrp * 4 + reg][cf * 16 + lcol] = f2bf(s[rf][cf][reg]);
  __syncthreads();

  f32x4 acc[2][4];
#pragma unroll
  for (int rf = 0; rf < 2; ++rf)
#pragma unroll
    for (int df = 0; df < 4; ++df) {
      acc[rf][df][0] = 0.f; acc[rf][df][1] = 0.f; acc[rf][df][2] = 0.f; acc[rf][df][3] = 0.f;
    }
#pragma unroll
  for (int ks = 0; ks < 2; ++ks) {
    bf16x8 pa[2], vb[4];
#pragma unroll
    for (int rf = 0; rf < 2; ++rf)
      pa[rf] = *(const bf16x8*)&Pb[wave][rf * 16 + lcol][ks * 32 + lgrp * 8];
#pragma unroll
    for (int df = 0; df < 4; ++df)
      vb[df] = *(const bf16x8*)&Vt[df * 16 + lcol][ks * 32 + lgrp * 8];
#pragma unroll
    for (int rf = 0; rf < 2; ++rf)
#pragma unroll
      for (int df = 0; df < 4; ++df)
        acc[rf][df] = __builtin_amdgcn_mfma_f32_16x16x32_bf16(pa[rf], vb[df], acc[rf][df], 0, 0, 0);
  }
#pragma unroll
  for (int rf = 0; rf < 2; ++rf)
#pragma unroll
    for (int reg = 0; reg < 4; ++reg) {
      const int qrow = qbase + rf * 16 + lgrp * 4 + reg;
      const float inv = inv_l[rf][reg];
#pragma unroll
      for (int df = 0; df < 4; ++df)
        CTX[((size_t)(b * S + qrow)) * H + h * 64 + df * 16 + lcol] =
            f2bf(acc[rf][df][reg] * inv);
    }
}

// ---------- residual + LayerNorm ----------
template<bool CF32, bool RF32, bool OF32>
__global__ __launch_bounds__(256) void ln_res(
    const void* __restrict__ C, const void* __restrict__ Res,
    const float* __restrict__ G, const float* __restrict__ Bb,
    void* __restrict__ Out)
{
  const int H = 1024;
  const int row = blockIdx.x;
  const int tid = threadIdx.x;
  float x[4];
  {
    float c4[4], r4[4];
    if (CF32) {
      const float4 c = reinterpret_cast<const float4*>((const float*)C + (size_t)row * H)[tid];
      c4[0] = c.x; c4[1] = c.y; c4[2] = c.z; c4[3] = c.w;
    } else {
      const uint2 cu = reinterpret_cast<const uint2*>((const u16*)C + (size_t)row * H)[tid];
      c4[0] = __uint_as_float(cu.x << 16); c4[1] = __uint_as_float(cu.x & 0xffff0000u);
      c4[2] = __uint_as_float(cu.y << 16); c4[3] = __uint_as_float(cu.y & 0xffff0000u);
    }
    if (RF32) {
      const float4 rr = reinterpret_cast<const float4*>((const float*)Res + (size_t)row * H)[tid];
      r4[0] = rr.x; r4[1] = rr.y; r4[2] = rr.z; r4[3] = rr.w;
    } else {
      const uint2 ru = reinterpret_cast<const uint2*>((const u16*)Res + (size_t)row * H)[tid];
      r4[0] = __uint_as_float(ru.x << 16); r4[1] = __uint_as_float(ru.x & 0xffff0000u);
      r4[2] = __uint_as_float(ru.y << 16); r4[3] = __uint_as_float(ru.y & 0xffff0000u);
    }
#pragma unroll
    for (int i = 0; i < 4; ++i) x[i] = c4[i] + r4[i];
  }
  float s = x[0] + x[1] + x[2] + x[3];
  float q = x[0] * x[0] + x[1] * x[1] + x[2] * x[2] + x[3] * x[3];
#pragma unroll
  for (int off = 1; off < 64; off <<= 1) {
    s += __shfl_xor(s, off);
    q += __shfl_xor(q, off);
  }
  __shared__ float sb[4][2];
  const int wid = tid >> 6;
  if ((tid & 63) == 0) { sb[wid][0] = s; sb[wid][1] = q; }
  __syncthreads();
  s = sb[0][0] + sb[1][0] + sb[2][0] + sb[3][0];
  q = sb[0][1] + sb[1][1] + sb[2][1] + sb[3][1];
  const float mean = s * (1.f / 1024.f);
  const float var = q * (1.f / 1024.f) - mean * mean;
  const float rstd = rsqrtf(fmaxf(var, 0.f) + 1e-12f);
  const float4 g4 = reinterpret_cast<const float4*>(G)[tid];
  const float4 b4 = reinterpret_cast<const float4*>(Bb)[tid];
  float o[4];
  o[0] = (x[0] - mean) * rstd * g4.x + b4.x;
  o[1] = (x[1] - mean) * rstd * g4.y + b4.y;
  o[2] = (x[2] - mean) * rstd * g4.z + b4.z;
  o[3] = (x[3] - mean) * rstd * g4.w + b4.w;
  if (OF32) {
    reinterpret_cast<float4*>((float*)Out + (size_t)row * H)[tid] =
        make_float4(o[0], o[1], o[2], o[3]);
  } else {
    uint2 pk;
    pk.x = ((u32)f2bf(o[0])) | (((u32)f2bf(o[1])) << 16);
    pk.y = ((u32)f2bf(o[2])) | (((u32)f2bf(o[3])) << 16);
    reinterpret_cast<uint2*>((u16*)Out + (size_t)row * H)[tid] = pk;
  }
}

// ---------- tag gather ----------
__global__ void gather_tags(const float* __restrict__ emb, const int* __restrict__ ids,
                            u16* __restrict__ tags)
{
  const int t = blockIdx.x;
  const int id = ids[t];
  const float4* src = reinterpret_cast<const float4*>(emb + (size_t)id * 1024);
  const float4 a = src[threadIdx.x * 2], b = src[threadIdx.x * 2 + 1];
  const float f[8] = {a.x, a.y, a.z, a.w, b.x, b.y, b.z, b.w};
  reinterpret_cast<uint4*>(tags + (size_t)t * 1024)[threadIdx.x] = pack8(f);
}

// ---------- host ----------
extern "C" void kernel_launch(void* const* d_in, const int* in_sizes, int n_in,
                              void* d_out, int out_size, void* d_ws, size_t ws_size,
                              hipStream_t stream)
{
  const int B = 4, S = 2048, H = 1024, FFN = 4096, T = 50;
  const int M = B * S;

  const bool dict_order = (in_sizes[10] == H * H);
  int i_cqw, i_cqb, i_ckw, i_ckb, i_cvw, i_cvb, i_cow, i_cob;
  int i_slng, i_slnb, i_clng, i_clnb, i_olng, i_olnb;
  int i_iw, i_ib, i_ow, i_ob;
  if (dict_order) {
    i_cqw = 10; i_cqb = 11; i_ckw = 12; i_ckb = 13; i_cvw = 14; i_cvb = 15; i_cow = 16; i_cob = 17;
    i_slng = 18; i_slnb = 19; i_clng = 20; i_clnb = 21; i_olng = 22; i_olnb = 23;
    i_iw = 24; i_ib = 25; i_ow = 26; i_ob = 27;
  } else {
    i_slng = 10; i_slnb = 11;
    i_cqw = 12; i_cqb = 13; i_ckw = 14; i_ckb = 15; i_cvw = 16; i_cvb = 17; i_cow = 18; i_cob = 19;
    i_clng = 20; i_clnb = 21;
    i_iw = 22; i_ib = 23; i_ow = 24; i_ob = 25; i_olng = 26; i_olnb = 27;
  }
  const float* X    = (const float*)d_in[0];
  const float* EMB  = (const float*)d_in[1];
  const float* SQW  = (const float*)d_in[2];
  const float* SQB  = (const float*)d_in[3];
  const float* SKW  = (const float*)d_in[4];
  const float* SKB  = (const float*)d_in[5];
  const float* SVW  = (const float*)d_in[6];
  const float* SVB  = (const float*)d_in[7];
  const float* SOW  = (const float*)d_in[8];
  const float* SOB  = (const float*)d_in[9];
  const float* CQW  = (const float*)d_in[i_cqw];
  const float* CQB  = (const float*)d_in[i_cqb];
  const float* CKW  = (const float*)d_in[i_ckw];
  const float* CKB  = (const float*)d_in[i_ckb];
  const float* CVW  = (const float*)d_in[i_cvw];
  const float* CVB  = (const float*)d_in[i_cvb];
  const float* COW  = (const float*)d_in[i_cow];
  const float* COB  = (const float*)d_in[i_cob];
  const float* SLNG = (const float*)d_in[i_slng];
  const float* SLNB = (const float*)d_in[i_slnb];
  const float* CLNG = (const float*)d_in[i_clng];
  const float* CLNB = (const float*)d_in[i_clnb];
  const float* OLNG = (const float*)d_in[i_olng];
  const float* OLNB = (const float*)d_in[i_olnb];
  const float* IW   = (const float*)d_in[i_iw];
  const float* IB   = (const float*)d_in[i_ib];
  const float* OW   = (const float*)d_in[i_ow];
  const float* OB   = (const float*)d_in[i_ob];
  const int* IDS  = (const int*)d_in[28];
  const int* RNG  = (const int*)d_in[29];

  char* ws = (char*)d_ws;
  u16* tags  = (u16*)(ws);                       // 100 KB
  u16* kvtag = (u16*)(ws + (1 << 17));           // 200 KB  [50][2048]
  float* bqkv = (float*)(ws + (3 << 17));        // 12 KB
  float* bckv = (float*)(ws + (3 << 17) + 16384);// 8 KB
  char* wreg = ws + (4 << 17);
  const size_t WHH = (size_t)H * H * 2;
  u16* wsq = (u16*)(wreg);            // wsq,wsk,wsv contiguous -> QKV weight [3072][1024]
  u16* wsk = (u16*)(wreg + WHH);
  u16* wsv = (u16*)(wreg + 2 * WHH);
  u16* wso = (u16*)(wreg + 3 * WHH);
  u16* wcq = (u16*)(wreg + 4 * WHH);
  u16* wck = (u16*)(wreg + 5 * WHH);  // wck,wcv contiguous -> KV weight [2048][1024]
  u16* wcv = (u16*)(wreg + 6 * WHH);
  u16* wco = (u16*)(wreg + 7 * WHH);
  u16* wit = (u16*)(wreg + 8 * WHH);
  u16* wot = (u16*)(wreg + 8 * WHH + (size_t)H * FFN * 2);
  char* slots = wreg + 8 * WHH + 2 * (size_t)H * FFN * 2;
  const size_t SZ = (size_t)M * H * 2;
  u16* s0 = (u16*)(slots);
  u16* s1 = (u16*)(slots + SZ);
  u16* s2 = (u16*)(slots + 2 * SZ);
  u16* s3 = (u16*)(slots + 3 * SZ);
  u16* s4 = (u16*)(slots + 4 * SZ);
  u16* qkv = s0;                      // packed [M][3072] spans s0..s2
  u16* inter = s0;                    // [M][FFN] spans s0..s3
  float* outp = (float*)d_out;

  const dim3 blk(256);
  const dim3 gsq(H / 128, M / 128);

  conv_bf16<<<dim3((M * H / 4 + 255) / 256), blk, 0, stream>>>(X, s4, M * H / 4);
  transpose_conv8<<<dim3(H / 32, H / 32, 8), blk, 0, stream>>>(
      SQW, SKW, SVW, SOW, CQW, CKW, CVW, COW,
      wsq, wsk, wsv, wso, wcq, wck, wcv, wco);
  transpose_conv<<<dim3(FFN / 32, H / 32), blk, 0, stream>>>(IW, wit, H, FFN);
  transpose_conv<<<dim3(H / 32, FFN / 32), blk, 0, stream>>>(OW, wot, FFN, H);
  pack_bias<<<dim3(5), blk, 0, stream>>>(SQB, SKB, SVB, CKB, CVB, bqkv, bckv);

  // --- self-attention block ---
  gemm_mfma_g<<<dim3(3 * H / 128, M / 128), blk, 0, stream>>>(
      s4, wsq, bqkv, qkv, M, 3 * H, H, 0, 0);                             // fused QKV
  attn_self_mfma<<<dim3(S / 128, 16, B), blk, 0, stream>>>(qkv, s3, RNG);
  gemm_mfma_g<<<gsq, blk, 0, stream>>>(s3, wso, SOB, s0, M, H, H, 0, 1);  // so_out
  ln_res<false, false, false><<<dim3(M), blk, 0, stream>>>(s0, s4, SLNG, SLNB, s3);  // Res = bf16(X)

  // --- cross-attention block ---
  gather_tags<<<dim3(T), dim3(128), 0, stream>>>(EMB, IDS, tags);
  gemm_mfma_k<<<dim3(2 * H / 128, 1), blk, 0, stream>>>(tags, wck, bckv, kvtag, T, 2 * H, H, 0);  // fused tag K/V
  gemm_mfma_g<<<gsq, blk, 0, stream>>>(s3, wcq, CQB, s0, M, H, H, 0, 1);  // cq
  attn_cross_mfma<<<dim3(S / 128, 16, B), blk, 0, stream>>>(s0, kvtag, s1);
  gemm_mfma_g<<<gsq, blk, 0, stream>>>(s1, wco, COB, s2, M, H, H, 0, 1);  // co_out
  ln_res<false, false, false><<<dim3(M), blk, 0, stream>>>(s2, s3, CLNG, CLNB, s4);

  // --- FFN block ---
  gemm_mfma_g<<<dim3(FFN / 128, M / 128), blk, 0, stream>>>(s4, wit, IB, inter, M, FFN, H, 1, 0);
  gemm_mfma_g<<<gsq, blk, 0, stream>>>(inter, wot, OB, outp, M, H, FFN, 2, 0);
  ln_res<true, false, true><<<dim3(M), blk, 0, stream>>>(outp, s4, OLNG, OLNB, outp);
}

// Round 19
// 572.044 us; speedup vs baseline: 1.0074x; 1.0074x over previous
//
#include <hip/hip_runtime.h>
#include <cstddef>

using u16 = unsigned short;
using u32 = unsigned int;
typedef short bf16x8 __attribute__((ext_vector_type(8)));
typedef float f32x4 __attribute__((ext_vector_type(4)));

// ---------- bf16 helpers ----------
__device__ __forceinline__ u16 f2bf(float f) {
  u32 x = __float_as_uint(f);
  return (u16)((x + 0x7fffu + ((x >> 16) & 1u)) >> 16);  // RNE
}
__device__ __forceinline__ uint4 pack8(const float* f) {
  uint4 r;
  r.x = ((u32)f2bf(f[0])) | (((u32)f2bf(f[1])) << 16);
  r.y = ((u32)f2bf(f[2])) | (((u32)f2bf(f[3])) << 16);
  r.z = ((u32)f2bf(f[4])) | (((u32)f2bf(f[5])) << 16);
  r.w = ((u32)f2bf(f[6])) | (((u32)f2bf(f[7])) << 16);
  return r;
}
__device__ __forceinline__ float fast_exp2(float x) {
  float r; asm("v_exp_f32 %0, %1" : "=v"(r) : "v"(x)); return r;
}
__device__ __forceinline__ float gelu_f(float x) {
  const float u = x * (0.7978845608f + 0.0356774081f * x * x);
  const float e = fast_exp2(u * 2.8853900818f);  // exp(2u)
  const float t = 1.f - 2.f / (e + 1.f);
  return 0.5f * x * (1.f + t);
}
__device__ __forceinline__ void gload16(const void* g, void* l) {
  __builtin_amdgcn_global_load_lds(
      (const __attribute__((address_space(1))) u32*)g,
      (__attribute__((address_space(3))) u32*)l, 16, 0, 0);
}

// ---------- MFMA GEMM (M%128==0), BK=64: C = epi(A[M,K] @ Wt[N,K]^T + bias) ----------
__global__ __launch_bounds__(256, 3) void gemm_mfma_g(
    const u16* __restrict__ A, const u16* __restrict__ Wt,
    const float* __restrict__ bias, void* __restrict__ Cout,
    int M, int N, int K, int outmode, int swz)
{
  __shared__ u16 As[128 * 64];
  __shared__ u16 Bs[128 * 64];
  const int tid = threadIdx.x;
  const int wave = tid >> 6, lane = tid & 63;
  const int wr = wave >> 1, wc = wave & 1;

  int xt, yt;
  if (swz) {
    const int lin = blockIdx.y * gridDim.x + blockIdx.x;
    const int k = lin & 7, j = lin >> 3;
    const int xw = gridDim.x;
    yt = 8 * k + j / xw;
    xt = j - (j / xw) * xw;
  } else {
    xt = blockIdx.x; yt = blockIdx.y;
  }
  const int m0 = yt * 128, n0 = xt * 128;
  const int lrow = lane & 15, lk = lane >> 4;

  const int rr = lane >> 3;        // 0..7
  const int cb = (lane & 7) * 16;  // byte col 0..112

  f32x4 acc[4][4];
#pragma unroll
  for (int i = 0; i < 4; ++i)
#pragma unroll
    for (int j = 0; j < 4; ++j) {
      acc[i][j][0] = 0.f; acc[i][j][1] = 0.f; acc[i][j][2] = 0.f; acc[i][j][3] = 0.f;
    }

  for (int k0 = 0; k0 < K; k0 += 64) {
    __syncthreads();
#pragma unroll
    for (int i = 0; i < 4; ++i) {
      const int Rloc = wave * 32 + i * 8 + rr;
      const int scb = cb ^ ((Rloc & 7) << 4);
      gload16(A + (size_t)(m0 + Rloc) * K + k0 + (scb >> 1),
              &As[(wave * 32 + i * 8) * 64]);
      gload16(Wt + (size_t)(n0 + Rloc) * K + k0 + (scb >> 1),
              &Bs[(wave * 32 + i * 8) * 64]);
    }
    __syncthreads();

#pragma unroll
    for (int kk = 0; kk < 2; ++kk) {
      bf16x8 af[4], bf[4];
#pragma unroll
      for (int i = 0; i < 4; ++i) {
        const int rA = wr * 64 + i * 16 + lrow;
        af[i] = *(const bf16x8*)&As[rA * 64 + (((kk * 64 + lk * 16) ^ ((rA & 7) << 4)) >> 1)];
        const int rB = wc * 64 + i * 16 + lrow;
        bf[i] = *(const bf16x8*)&Bs[rB * 64 + (((kk * 64 + lk * 16) ^ ((rB & 7) << 4)) >> 1)];
      }
#pragma unroll
      for (int i = 0; i < 4; ++i)
#pragma unroll
        for (int j = 0; j < 4; ++j)
          acc[i][j] = __builtin_amdgcn_mfma_f32_16x16x32_bf16(af[i], bf[j], acc[i][j], 0, 0, 0);
    }
  }

#pragma unroll
  for (int j = 0; j < 4; ++j) {
    const int gcol = n0 + wc * 64 + j * 16 + lrow;
    const float bj = bias[gcol];
#pragma unroll
    for (int i = 0; i < 4; ++i) {
      const int rbase = m0 + wr * 64 + i * 16 + lk * 4;
#pragma unroll
      for (int reg = 0; reg < 4; ++reg) {
        float c = acc[i][j][reg] + bj;
        if (outmode == 1) c = gelu_f(c);
        if (outmode == 2)
          ((float*)Cout)[(size_t)(rbase + reg) * N + gcol] = c;
        else
          ((u16*)Cout)[(size_t)(rbase + reg) * N + gcol] = f2bf(c);
      }
    }
  }
}

// ---------- MFMA GEMM, guarded (small M, e.g. tags M=50) ----------
__global__ __launch_bounds__(256, 2) void gemm_mfma_k(
    const u16* __restrict__ A, const u16* __restrict__ Wt,
    const float* __restrict__ bias, void* __restrict__ Cout,
    int M, int N, int K, int outmode)
{
  __shared__ u16 As[128][40];
  __shared__ u16 Bs[128][40];
  const int tid = threadIdx.x;
  const int wave = tid >> 6, lane = tid & 63;
  const int wr = wave >> 1, wc = wave & 1;
  const int m0 = blockIdx.y * 128, n0 = blockIdx.x * 128;
  const int lrow = lane & 15, lk = lane >> 4;

  f32x4 acc[4][4];
#pragma unroll
  for (int i = 0; i < 4; ++i)
#pragma unroll
    for (int j = 0; j < 4; ++j) {
      acc[i][j][0] = 0.f; acc[i][j][1] = 0.f; acc[i][j][2] = 0.f; acc[i][j][3] = 0.f;
    }

  const int sr = tid >> 2;
  const int sk = (tid & 3) * 8;
  const bool arow_ok0 = (m0 + sr) < M;
  const bool arow_ok1 = (m0 + sr + 64) < M;

  for (int k0 = 0; k0 < K; k0 += 32) {
    __syncthreads();
    if (arow_ok0)
      *(uint4*)&As[sr][sk] = *(const uint4*)&A[(size_t)(m0 + sr) * K + k0 + sk];
    if (arow_ok1)
      *(uint4*)&As[sr + 64][sk] = *(const uint4*)&A[(size_t)(m0 + sr + 64) * K + k0 + sk];
    *(uint4*)&Bs[sr][sk] = *(const uint4*)&Wt[(size_t)(n0 + sr) * K + k0 + sk];
    *(uint4*)&Bs[sr + 64][sk] = *(const uint4*)&Wt[(size_t)(n0 + sr + 64) * K + k0 + sk];
    __syncthreads();

    bf16x8 af[4], bf[4];
#pragma unroll
    for (int i = 0; i < 4; ++i) {
      af[i] = *(const bf16x8*)&As[wr * 64 + i * 16 + lrow][lk * 8];
      bf[i] = *(const bf16x8*)&Bs[wc * 64 + i * 16 + lrow][lk * 8];
    }
#pragma unroll
    for (int i = 0; i < 4; ++i)
#pragma unroll
      for (int j = 0; j < 4; ++j)
        acc[i][j] = __builtin_amdgcn_mfma_f32_16x16x32_bf16(af[i], bf[j], acc[i][j], 0, 0, 0);
  }

#pragma unroll
  for (int j = 0; j < 4; ++j) {
    const int gcol = n0 + wc * 64 + j * 16 + lrow;
    const float bj = bias[gcol];
#pragma unroll
    for (int i = 0; i < 4; ++i) {
      const int rbase = m0 + wr * 64 + i * 16 + lk * 4;
#pragma unroll
      for (int reg = 0; reg < 4; ++reg) {
        const int grow = rbase + reg;
        if (grow >= M) continue;
        float c = acc[i][j][reg] + bj;
        if (outmode == 1) c = gelu_f(c);
        if (outmode == 2)
          ((float*)Cout)[(size_t)grow * N + gcol] = c;
        else
          ((u16*)Cout)[(size_t)grow * N + gcol] = f2bf(c);
      }
    }
  }
}

// ---------- weight transpose+convert (single) ----------
__global__ __launch_bounds__(256) void transpose_conv(
    const float* __restrict__ W, u16* __restrict__ Wt, int K, int N)
{
  __shared__ float t[32][33];
  const int kb = blockIdx.y * 32, nb = blockIdx.x * 32;
  const int x = threadIdx.x & 31;
  const int y4 = (threadIdx.x >> 5) * 4;
#pragma unroll
  for (int i = 0; i < 4; ++i)
    t[y4 + i][x] = W[(size_t)(kb + y4 + i) * N + nb + x];
  __syncthreads();
#pragma unroll
  for (int i = 0; i < 4; ++i)
    Wt[(size_t)(nb + y4 + i) * K + kb + x] = f2bf(t[x][y4 + i]);
}

// ---------- batched 1024x1024 weight transpose+convert (8 matrices) ----------
__global__ __launch_bounds__(256) void transpose_conv8(
    const float* w0, const float* w1, const float* w2, const float* w3,
    const float* w4, const float* w5, const float* w6, const float* w7,
    u16* t0, u16* t1, u16* t2, u16* t3,
    u16* t4, u16* t5, u16* t6, u16* t7)
{
  const int K = 1024, N = 1024;
  const float* W; u16* Wt;
  switch (blockIdx.z) {
    case 0: W = w0; Wt = t0; break;
    case 1: W = w1; Wt = t1; break;
    case 2: W = w2; Wt = t2; break;
    case 3: W = w3; Wt = t3; break;
    case 4: W = w4; Wt = t4; break;
    case 5: W = w5; Wt = t5; break;
    case 6: W = w6; Wt = t6; break;
    default: W = w7; Wt = t7; break;
  }
  __shared__ float t[32][33];
  const int kb = blockIdx.y * 32, nb = blockIdx.x * 32;
  const int x = threadIdx.x & 31;
  const int y4 = (threadIdx.x >> 5) * 4;
#pragma unroll
  for (int i = 0; i < 4; ++i)
    t[y4 + i][x] = W[(size_t)(kb + y4 + i) * N + nb + x];
  __syncthreads();
#pragma unroll
  for (int i = 0; i < 4; ++i)
    Wt[(size_t)(nb + y4 + i) * K + kb + x] = f2bf(t[x][y4 + i]);
}

// ---------- elementwise fp32 -> bf16 ----------
__global__ __launch_bounds__(256) void conv_bf16(
    const float* __restrict__ in, u16* __restrict__ out, int n4)
{
  const int idx = blockIdx.x * 256 + threadIdx.x;
  if (idx >= n4) return;
  const float4 v = reinterpret_cast<const float4*>(in)[idx];
  const float f[4] = {v.x, v.y, v.z, v.w};
  uint2 pk;
  pk.x = ((u32)f2bf(f[0])) | (((u32)f2bf(f[1])) << 16);
  pk.y = ((u32)f2bf(f[2])) | (((u32)f2bf(f[3])) << 16);
  reinterpret_cast<uint2*>(out)[idx] = pk;
}

// ---------- bias packing: bqkv[3072] = {sqb,skb,svb}; bckv[2048] = {ckb,cvb} ----------
__global__ __launch_bounds__(256) void pack_bias(
    const float* __restrict__ sqb, const float* __restrict__ skb,
    const float* __restrict__ svb, const float* __restrict__ ckb,
    const float* __restrict__ cvb, float* __restrict__ bqkv,
    float* __restrict__ bckv)
{
  const int t = threadIdx.x;
  switch (blockIdx.x) {
    case 0: ((float4*)bqkv)[t] = ((const float4*)sqb)[t]; break;
    case 1: ((float4*)(bqkv + 1024))[t] = ((const float4*)skb)[t]; break;
    case 2: ((float4*)(bqkv + 2048))[t] = ((const float4*)svb)[t]; break;
    case 3: ((float4*)bckv)[t] = ((const float4*)ckb)[t]; break;
    default: ((float4*)(bckv + 1024))[t] = ((const float4*)cvb)[t]; break;
  }
}

// ---------- MFMA flash self-attention (packed QKV[M][3072]) ----------
// T14 async-STAGE split: V global load ISSUED right after the barrier,
// consumed (written to LDS) only after QK^T+softmax -> HBM/L2 latency hides
// under MFMA+exp2 work. Same barrier semantics as before (pure code motion).
__global__ __launch_bounds__(256, 4) void attn_self_mfma(
    const u16* __restrict__ QKV, u16* __restrict__ CTX,
    const int* __restrict__ rngp)
{
  const int S = 2048, H = 1024, SD = 3072;
  const float SC = 0.125f * 1.44269504f;
  const float MB = 1.44269504f;
  const int qt = blockIdx.x, h = blockIdx.y, b = blockIdx.z;
  const int range = rngp[0];
  const int tid = threadIdx.x;
  const int wave = tid >> 6, lane = tid & 63;
  const int lcol = lane & 15;
  const int lgrp = lane >> 4;

  __shared__ u16 Vt[64][72];
  __shared__ u16 Pb[4][32][72];

  const int qbase = qt * 128 + wave * 32;
  const u16* Kp = QKV + 1024;
  const u16* Vp = QKV + 2048;

  bf16x8 qf[2][2];
#pragma unroll
  for (int rf = 0; rf < 2; ++rf)
#pragma unroll
    for (int dh = 0; dh < 2; ++dh) {
      const int qrow = qbase + rf * 16 + lcol;
      qf[rf][dh] = *(const bf16x8*)&QKV[((size_t)(b * S + qrow)) * SD + h * 64 + dh * 32 + lgrp * 8];
    }

  f32x4 acc[2][4];
#pragma unroll
  for (int rf = 0; rf < 2; ++rf)
#pragma unroll
    for (int df = 0; df < 4; ++df) {
      acc[rf][df][0] = 0.f; acc[rf][df][1] = 0.f; acc[rf][df][2] = 0.f; acc[rf][df][3] = 0.f;
    }
  float lreg[2][4];
#pragma unroll
  for (int rf = 0; rf < 2; ++rf)
#pragma unroll
    for (int reg = 0; reg < 4; ++reg) lreg[rf][reg] = 0.f;

  for (int c = 0; c < 32; ++c) {
    const int kb = c * 64;
    __syncthreads();
    // --- issue V load early (global -> regs), consume after softmax ---
    const u16* vsrc = &Vp[((size_t)(b * S + kb + lane)) * SD + h * 64 + wave * 16];
    const uint4 vu0 = *(const uint4*)vsrc;
    const uint4 vu1 = *(const uint4*)(vsrc + 8);
    // --- QK^T ---
    f32x4 s[2][4];
#pragma unroll
    for (int rf = 0; rf < 2; ++rf)
#pragma unroll
      for (int cf = 0; cf < 4; ++cf) {
        s[rf][cf][0] = 0.f; s[rf][cf][1] = 0.f; s[rf][cf][2] = 0.f; s[rf][cf][3] = 0.f;
      }
#pragma unroll
    for (int dh = 0; dh < 2; ++dh)
#pragma unroll
      for (int cf = 0; cf < 4; ++cf) {
        const int krow = kb + cf * 16 + lcol;
        const bf16x8 kf = *(const bf16x8*)&Kp[((size_t)(b * S + krow)) * SD + h * 64 + dh * 32 + lgrp * 8];
#pragma unroll
        for (int rf = 0; rf < 2; ++rf)
          s[rf][cf] = __builtin_amdgcn_mfma_f32_16x16x32_bf16(qf[rf][dh], kf, s[rf][cf], 0, 0, 0);
      }
    // --- softmax (no-max, deferred l-reduce) ---
#pragma unroll
    for (int rf = 0; rf < 2; ++rf) {
#pragma unroll
      for (int reg = 0; reg < 4; ++reg) {
        const int qrow = qbase + rf * 16 + lgrp * 4 + reg;
#pragma unroll
        for (int cf = 0; cf < 4; ++cf) {
          const int kcol = kb + cf * 16 + lcol;
          int dd = qrow - kcol; if (dd < 0) dd = -dd;
          const float e = fast_exp2(s[rf][cf][reg] * SC + ((dd <= range) ? MB : 0.0f));
          s[rf][cf][reg] = e;
          lreg[rf][reg] += e;
        }
      }
    }
#pragma unroll
    for (int rf = 0; rf < 2; ++rf)
#pragma unroll
      for (int reg = 0; reg < 4; ++reg)
#pragma unroll
        for (int cf = 0; cf < 4; ++cf)
          Pb[wave][rf * 16 + lgrp * 4 + reg][cf * 16 + lcol] =
              (u16)(__float_as_uint(s[rf][cf][reg]) >> 16);
    // --- NOW write V to LDS (load arrived long ago) ---
    {
      u16 tmp[16];
      *(uint4*)tmp = vu0; *(uint4*)(tmp + 8) = vu1;
#pragma unroll
      for (int i = 0; i < 16; ++i) Vt[wave * 16 + i][lane] = tmp[i];
    }
    __syncthreads();
    // --- PV ---
#pragma unroll
    for (int ks = 0; ks < 2; ++ks) {
      bf16x8 pa[2], vb[4];
#pragma unroll
      for (int rf = 0; rf < 2; ++rf)
        pa[rf] = *(const bf16x8*)&Pb[wave][rf * 16 + lcol][ks * 32 + lgrp * 8];
#pragma unroll
      for (int df = 0; df < 4; ++df)
        vb[df] = *(const bf16x8*)&Vt[df * 16 + lcol][ks * 32 + lgrp * 8];
#pragma unroll
      for (int rf = 0; rf < 2; ++rf)
#pragma unroll
        for (int df = 0; df < 4; ++df)
          acc[rf][df] = __builtin_amdgcn_mfma_f32_16x16x32_bf16(pa[rf], vb[df], acc[rf][df], 0, 0, 0);
    }
  }
#pragma unroll
  for (int rf = 0; rf < 2; ++rf)
#pragma unroll
    for (int reg = 0; reg < 4; ++reg) {
      float l = lreg[rf][reg];
      l += __shfl_xor(l, 1);
      l += __shfl_xor(l, 2);
      l += __shfl_xor(l, 4);
      l += __shfl_xor(l, 8);
      lreg[rf][reg] = l;
    }
#pragma unroll
  for (int rf = 0; rf < 2; ++rf)
#pragma unroll
    for (int reg = 0; reg < 4; ++reg) {
      const int qrow = qbase + rf * 16 + lgrp * 4 + reg;
      const float inv = 1.f / lreg[rf][reg];
#pragma unroll
      for (int df = 0; df < 4; ++df)
        CTX[((size_t)(b * S + qrow)) * H + h * 64 + df * 16 + lcol] =
            f2bf(acc[rf][df][reg] * inv);
    }
}

// ---------- MFMA cross-attention: packed KV[50][2048] (K at 0, V at +1024) ----------
__global__ __launch_bounds__(256, 4) void attn_cross_mfma(
    const u16* __restrict__ Q, const u16* __restrict__ KV,
    u16* __restrict__ CTX)
{
  const int S = 2048, H = 1024, T = 50, KD = 2048;
  const float SC = 0.125f * 1.44269504f;
  const int qt = blockIdx.x, h = blockIdx.y, b = blockIdx.z;
  const int tid = threadIdx.x;
  const int wave = tid >> 6, lane = tid & 63;
  const int lcol = lane & 15;
  const int lgrp = lane >> 4;

  __shared__ u16 Vt[64][72];
  __shared__ u16 Pb[4][32][72];

  const int qbase = qt * 128 + wave * 32;

  bf16x8 qf[2][2];
#pragma unroll
  for (int rf = 0; rf < 2; ++rf)
#pragma unroll
    for (int dh = 0; dh < 2; ++dh) {
      const int qrow = qbase + rf * 16 + lcol;
      qf[rf][dh] = *(const bf16x8*)&Q[((size_t)(b * S + qrow)) * H + h * 64 + dh * 32 + lgrp * 8];
    }

  {
    u16 tmp[16];
    if (lane < T) {
      const u16* vsrc = &KV[(size_t)lane * KD + 1024 + h * 64 + wave * 16];
      *(uint4*)tmp = *(const uint4*)vsrc;
      *(uint4*)(tmp + 8) = *(const uint4*)(vsrc + 8);
    } else {
#pragma unroll
      for (int i = 0; i < 16; ++i) tmp[i] = 0;
    }
#pragma unroll
    for (int i = 0; i < 16; ++i) Vt[wave * 16 + i][lane] = tmp[i];
  }

  f32x4 s[2][4];
#pragma unroll
  for (int rf = 0; rf < 2; ++rf)
#pragma unroll
    for (int cf = 0; cf < 4; ++cf) {
      s[rf][cf][0] = 0.f; s[rf][cf][1] = 0.f; s[rf][cf][2] = 0.f; s[rf][cf][3] = 0.f;
    }
#pragma unroll
  for (int dh = 0; dh < 2; ++dh)
#pragma unroll
    for (int cf = 0; cf < 4; ++cf) {
      const int krow = cf * 16 + lcol;
      const bf16x8 kf = *(const bf16x8*)&KV[(size_t)krow * KD + h * 64 + dh * 32 + lgrp * 8];
#pragma unroll
      for (int rf = 0; rf < 2; ++rf)
        s[rf][cf] = __builtin_amdgcn_mfma_f32_16x16x32_bf16(qf[rf][dh], kf, s[rf][cf], 0, 0, 0);
    }

  float inv_l[2][4];
#pragma unroll
  for (int rf = 0; rf < 2; ++rf) {
#pragma unroll
    for (int reg = 0; reg < 4; ++reg) {
      float rmax = -1e30f;
#pragma unroll
      for (int cf = 0; cf < 4; ++cf) {
        const int kcol = cf * 16 + lcol;
        const float v = (kcol < T) ? s[rf][cf][reg] * SC : -1e30f;
        s[rf][cf][reg] = v;
        rmax = fmaxf(rmax, v);
      }
      rmax = fmaxf(rmax, __shfl_xor(rmax, 1));
      rmax = fmaxf(rmax, __shfl_xor(rmax, 2));
      rmax = fmaxf(rmax, __shfl_xor(rmax, 4));
      rmax = fmaxf(rmax, __shfl_xor(rmax, 8));
      float rsum = 0.f;
#pragma unroll
      for (int cf = 0; cf < 4; ++cf) {
        const float e = fast_exp2(s[rf][cf][reg] - rmax);
        s[rf][cf][reg] = e;
        rsum += e;
      }
      rsum += __shfl_xor(rsum, 1);
      rsum += __shfl_xor(rsum, 2);
      rsum += __shfl_xor(rsum, 4);
      rsum += __shfl_xor(rsum, 8);
      inv_l[rf][reg] = 1.f / rsum;
    }
  }
#pragma unroll
  for (int rf = 0; rf < 2; ++rf)
#pragma unroll
    for (int reg = 0; reg < 4; ++reg)
#pragma unroll
      for (int cf = 0; cf < 4; ++cf)
        Pb[wave][rf * 16 + lgrp * 4 + reg][cf * 16 + lcol] = f2bf(s[rf][cf][reg]);
  __syncthreads();

  f32x4 acc[2][4];
#pragma unroll
  for (int rf = 0; rf < 2; ++rf)
#pragma unroll
    for (int df = 0; df < 4; ++df) {
      acc[rf][df][0] = 0.f; acc[rf][df][1] = 0.f; acc[rf][df][2] = 0.f; acc[rf][df][3] = 0.f;
    }
#pragma unroll
  for (int ks = 0; ks < 2; ++ks) {
    bf16x8 pa[2], vb[4];
#pragma unroll
    for (int rf = 0; rf < 2; ++rf)
      pa[rf] = *(const bf16x8*)&Pb[wave][rf * 16 + lcol][ks * 32 + lgrp * 8];
#pragma unroll
    for (int df = 0; df < 4; ++df)
      vb[df] = *(const bf16x8*)&Vt[df * 16 + lcol][ks * 32 + lgrp * 8];
#pragma unroll
    for (int rf = 0; rf < 2; ++rf)
#pragma unroll
      for (int df = 0; df < 4; ++df)
        acc[rf][df] = __builtin_amdgcn_mfma_f32_16x16x32_bf16(pa[rf], vb[df], acc[rf][df], 0, 0, 0);
  }
#pragma unroll
  for (int rf = 0; rf < 2; ++rf)
#pragma unroll
    for (int reg = 0; reg < 4; ++reg) {
      const int qrow = qbase + rf * 16 + lgrp * 4 + reg;
      const float inv = inv_l[rf][reg];
#pragma unroll
      for (int df = 0; df < 4; ++df)
        CTX[((size_t)(b * S + qrow)) * H + h * 64 + df * 16 + lcol] =
            f2bf(acc[rf][df][reg] * inv);
    }
}

// ---------- residual + LayerNorm ----------
template<bool CF32, bool RF32, bool OF32>
__global__ __launch_bounds__(256) void ln_res(
    const void* __restrict__ C, const void* __restrict__ Res,
    const float* __restrict__ G, const float* __restrict__ Bb,
    void* __restrict__ Out)
{
  const int H = 1024;
  const int row = blockIdx.x;
  const int tid = threadIdx.x;
  float x[4];
  {
    float c4[4], r4[4];
    if (CF32) {
      const float4 c = reinterpret_cast<const float4*>((const float*)C + (size_t)row * H)[tid];
      c4[0] = c.x; c4[1] = c.y; c4[2] = c.z; c4[3] = c.w;
    } else {
      const uint2 cu = reinterpret_cast<const uint2*>((const u16*)C + (size_t)row * H)[tid];
      c4[0] = __uint_as_float(cu.x << 16); c4[1] = __uint_as_float(cu.x & 0xffff0000u);
      c4[2] = __uint_as_float(cu.y << 16); c4[3] = __uint_as_float(cu.y & 0xffff0000u);
    }
    if (RF32) {
      const float4 rr = reinterpret_cast<const float4*>((const float*)Res + (size_t)row * H)[tid];
      r4[0] = rr.x; r4[1] = rr.y; r4[2] = rr.z; r4[3] = rr.w;
    } else {
      const uint2 ru = reinterpret_cast<const uint2*>((const u16*)Res + (size_t)row * H)[tid];
      r4[0] = __uint_as_float(ru.x << 16); r4[1] = __uint_as_float(ru.x & 0xffff0000u);
      r4[2] = __uint_as_float(ru.y << 16); r4[3] = __uint_as_float(ru.y & 0xffff0000u);
    }
#pragma unroll
    for (int i = 0; i < 4; ++i) x[i] = c4[i] + r4[i];
  }
  float s = x[0] + x[1] + x[2] + x[3];
  float q = x[0] * x[0] + x[1] * x[1] + x[2] * x[2] + x[3] * x[3];
#pragma unroll
  for (int off = 1; off < 64; off <<= 1) {
    s += __shfl_xor(s, off);
    q += __shfl_xor(q, off);
  }
  __shared__ float sb[4][2];
  const int wid = tid >> 6;
  if ((tid & 63) == 0) { sb[wid][0] = s; sb[wid][1] = q; }
  __syncthreads();
  s = sb[0][0] + sb[1][0] + sb[2][0] + sb[3][0];
  q = sb[0][1] + sb[1][1] + sb[2][1] + sb[3][1];
  const float mean = s * (1.f / 1024.f);
  const float var = q * (1.f / 1024.f) - mean * mean;
  const float rstd = rsqrtf(fmaxf(var, 0.f) + 1e-12f);
  const float4 g4 = reinterpret_cast<const float4*>(G)[tid];
  const float4 b4 = reinterpret_cast<const float4*>(Bb)[tid];
  float o[4];
  o[0] = (x[0] - mean) * rstd * g4.x + b4.x;
  o[1] = (x[1] - mean) * rstd * g4.y + b4.y;
  o[2] = (x[2] - mean) * rstd * g4.z + b4.z;
  o[3] = (x[3] - mean) * rstd * g4.w + b4.w;
  if (OF32) {
    reinterpret_cast<float4*>((float*)Out + (size_t)row * H)[tid] =
        make_float4(o[0], o[1], o[2], o[3]);
  } else {
    uint2 pk;
    pk.x = ((u32)f2bf(o[0])) | (((u32)f2bf(o[1])) << 16);
    pk.y = ((u32)f2bf(o[2])) | (((u32)f2bf(o[3])) << 16);
    reinterpret_cast<uint2*>((u16*)Out + (size_t)row * H)[tid] = pk;
  }
}

// ---------- tag gather ----------
__global__ void gather_tags(const float* __restrict__ emb, const int* __restrict__ ids,
                            u16* __restrict__ tags)
{
  const int t = blockIdx.x;
  const int id = ids[t];
  const float4* src = reinterpret_cast<const float4*>(emb + (size_t)id * 1024);
  const float4 a = src[threadIdx.x * 2], b = src[threadIdx.x * 2 + 1];
  const float f[8] = {a.x, a.y, a.z, a.w, b.x, b.y, b.z, b.w};
  reinterpret_cast<uint4*>(tags + (size_t)t * 1024)[threadIdx.x] = pack8(f);
}

// ---------- host ----------
extern "C" void kernel_launch(void* const* d_in, const int* in_sizes, int n_in,
                              void* d_out, int out_size, void* d_ws, size_t ws_size,
                              hipStream_t stream)
{
  const int B = 4, S = 2048, H = 1024, FFN = 4096, T = 50;
  const int M = B * S;

  const bool dict_order = (in_sizes[10] == H * H);
  int i_cqw, i_cqb, i_ckw, i_ckb, i_cvw, i_cvb, i_cow, i_cob;
  int i_slng, i_slnb, i_clng, i_clnb, i_olng, i_olnb;
  int i_iw, i_ib, i_ow, i_ob;
  if (dict_order) {
    i_cqw = 10; i_cqb = 11; i_ckw = 12; i_ckb = 13; i_cvw = 14; i_cvb = 15; i_cow = 16; i_cob = 17;
    i_slng = 18; i_slnb = 19; i_clng = 20; i_clnb = 21; i_olng = 22; i_olnb = 23;
    i_iw = 24; i_ib = 25; i_ow = 26; i_ob = 27;
  } else {
    i_slng = 10; i_slnb = 11;
    i_cqw = 12; i_cqb = 13; i_ckw = 14; i_ckb = 15; i_cvw = 16; i_cvb = 17; i_cow = 18; i_cob = 19;
    i_clng = 20; i_clnb = 21;
    i_iw = 22; i_ib = 23; i_ow = 24; i_ob = 25; i_olng = 26; i_olnb = 27;
  }
  const float* X    = (const float*)d_in[0];
  const float* EMB  = (const float*)d_in[1];
  const float* SQW  = (const float*)d_in[2];
  const float* SQB  = (const float*)d_in[3];
  const float* SKW  = (const float*)d_in[4];
  const float* SKB  = (const float*)d_in[5];
  const float* SVW  = (const float*)d_in[6];
  const float* SVB  = (const float*)d_in[7];
  const float* SOW  = (const float*)d_in[8];
  const float* SOB  = (const float*)d_in[9];
  const float* CQW  = (const float*)d_in[i_cqw];
  const float* CQB  = (const float*)d_in[i_cqb];
  const float* CKW  = (const float*)d_in[i_ckw];
  const float* CKB  = (const float*)d_in[i_ckb];
  const float* CVW  = (const float*)d_in[i_cvw];
  const float* CVB  = (const float*)d_in[i_cvb];
  const float* COW  = (const float*)d_in[i_cow];
  const float* COB  = (const float*)d_in[i_cob];
  const float* SLNG = (const float*)d_in[i_slng];
  const float* SLNB = (const float*)d_in[i_slnb];
  const float* CLNG = (const float*)d_in[i_clng];
  const float* CLNB = (const float*)d_in[i_clnb];
  const float* OLNG = (const float*)d_in[i_olng];
  const float* OLNB = (const float*)d_in[i_olnb];
  const float* IW   = (const float*)d_in[i_iw];
  const float* IB   = (const float*)d_in[i_ib];
  const float* OW   = (const float*)d_in[i_ow];
  const float* OB   = (const float*)d_in[i_ob];
  const int* IDS  = (const int*)d_in[28];
  const int* RNG  = (const int*)d_in[29];

  char* ws = (char*)d_ws;
  u16* tags  = (u16*)(ws);                       // 100 KB
  u16* kvtag = (u16*)(ws + (1 << 17));           // 200 KB  [50][2048]
  float* bqkv = (float*)(ws + (3 << 17));        // 12 KB
  float* bckv = (float*)(ws + (3 << 17) + 16384);// 8 KB
  char* wreg = ws + (4 << 17);
  const size_t WHH = (size_t)H * H * 2;
  u16* wsq = (u16*)(wreg);            // wsq,wsk,wsv contiguous -> QKV weight [3072][1024]
  u16* wsk = (u16*)(wreg + WHH);
  u16* wsv = (u16*)(wreg + 2 * WHH);
  u16* wso = (u16*)(wreg + 3 * WHH);
  u16* wcq = (u16*)(wreg + 4 * WHH);
  u16* wck = (u16*)(wreg + 5 * WHH);  // wck,wcv contiguous -> KV weight [2048][1024]
  u16* wcv = (u16*)(wreg + 6 * WHH);
  u16* wco = (u16*)(wreg + 7 * WHH);
  u16* wit = (u16*)(wreg + 8 * WHH);
  u16* wot = (u16*)(wreg + 8 * WHH + (size_t)H * FFN * 2);
  char* slots = wreg + 8 * WHH + 2 * (size_t)H * FFN * 2;
  const size_t SZ = (size_t)M * H * 2;
  u16* s0 = (u16*)(slots);
  u16* s1 = (u16*)(slots + SZ);
  u16* s2 = (u16*)(slots + 2 * SZ);
  u16* s3 = (u16*)(slots + 3 * SZ);
  u16* s4 = (u16*)(slots + 4 * SZ);
  u16* qkv = s0;                      // packed [M][3072] spans s0..s2
  u16* inter = s0;                    // [M][FFN] spans s0..s3
  float* outp = (float*)d_out;

  const dim3 blk(256);
  const dim3 gsq(H / 128, M / 128);

  conv_bf16<<<dim3((M * H / 4 + 255) / 256), blk, 0, stream>>>(X, s4, M * H / 4);
  transpose_conv8<<<dim3(H / 32, H / 32, 8), blk, 0, stream>>>(
      SQW, SKW, SVW, SOW, CQW, CKW, CVW, COW,
      wsq, wsk, wsv, wso, wcq, wck, wcv, wco);
  transpose_conv<<<dim3(FFN / 32, H / 32), blk, 0, stream>>>(IW, wit, H, FFN);
  transpose_conv<<<dim3(H / 32, FFN / 32), blk, 0, stream>>>(OW, wot, FFN, H);
  pack_bias<<<dim3(5), blk, 0, stream>>>(SQB, SKB, SVB, CKB, CVB, bqkv, bckv);

  // --- self-attention block ---
  gemm_mfma_g<<<dim3(3 * H / 128, M / 128), blk, 0, stream>>>(
      s4, wsq, bqkv, qkv, M, 3 * H, H, 0, 0);                             // fused QKV
  attn_self_mfma<<<dim3(S / 128, 16, B), blk, 0, stream>>>(qkv, s3, RNG);
  gemm_mfma_g<<<gsq, blk, 0, stream>>>(s3, wso, SOB, s0, M, H, H, 0, 1);  // so_out
  ln_res<false, false, false><<<dim3(M), blk, 0, stream>>>(s0, s4, SLNG, SLNB, s3);  // Res = bf16(X)

  // --- cross-attention block ---
  gather_tags<<<dim3(T), dim3(128), 0, stream>>>(EMB, IDS, tags);
  gemm_mfma_k<<<dim3(2 * H / 128, 1), blk, 0, stream>>>(tags, wck, bckv, kvtag, T, 2 * H, H, 0);  // fused tag K/V
  gemm_mfma_g<<<gsq, blk, 0, stream>>>(s3, wcq, CQB, s0, M, H, H, 0, 1);  // cq
  attn_cross_mfma<<<dim3(S / 128, 16, B), blk, 0, stream>>>(s0, kvtag, s1);
  gemm_mfma_g<<<gsq, blk, 0, stream>>>(s1, wco, COB, s2, M, H, H, 0, 1);  // co_out
  ln_res<false, false, false><<<dim3(M), blk, 0, stream>>>(s2, s3, CLNG, CLNB, s4);

  // --- FFN block ---
  gemm_mfma_g<<<dim3(FFN / 128, M / 128), blk, 0, stream>>>(s4, wit, IB, inter, M, FFN, H, 1, 0);
  gemm_mfma_g<<<gsq, blk, 0, stream>>>(inter, wot, OB, outp, M, H, FFN, 2, 0);
  ln_res<true, false, true><<<dim3(M), blk, 0, stream>>>(outp, s4, OLNG, OLNB, outp);
}

// Round 20
// 570.366 us; speedup vs baseline: 1.0104x; 1.0029x over previous
//
#include <hip/hip_runtime.h>
#include <cstddef>

using u16 = unsigned short;
using u32 = unsigned int;
typedef short bf16x8 __attribute__((ext_vector_type(8)));
typedef float f32x4 __attribute__((ext_vector_type(4)));

// ---------- bf16 helpers ----------
__device__ __forceinline__ u16 f2bf(float f) {
  u32 x = __float_as_uint(f);
  return (u16)((x + 0x7fffu + ((x >> 16) & 1u)) >> 16);  // RNE
}
__device__ __forceinline__ uint4 pack8(const float* f) {
  uint4 r;
  r.x = ((u32)f2bf(f[0])) | (((u32)f2bf(f[1])) << 16);
  r.y = ((u32)f2bf(f[2])) | (((u32)f2bf(f[3])) << 16);
  r.z = ((u32)f2bf(f[4])) | (((u32)f2bf(f[5])) << 16);
  r.w = ((u32)f2bf(f[6])) | (((u32)f2bf(f[7])) << 16);
  return r;
}
__device__ __forceinline__ float fast_exp2(float x) {
  float r; asm("v_exp_f32 %0, %1" : "=v"(r) : "v"(x)); return r;
}
__device__ __forceinline__ float gelu_f(float x) {
  const float u = x * (0.7978845608f + 0.0356774081f * x * x);
  const float e = fast_exp2(u * 2.8853900818f);  // exp(2u)
  const float t = 1.f - 2.f / (e + 1.f);
  return 0.5f * x * (1.f + t);
}
__device__ __forceinline__ void gload16(const void* g, void* l) {
  __builtin_amdgcn_global_load_lds(
      (const __attribute__((address_space(1))) u32*)g,
      (__attribute__((address_space(3))) u32*)l, 16, 0, 0);
}

// ---------- MFMA GEMM (M%128==0), BK=64: C = epi(A[M,K] @ Wt[N,K]^T + bias) ----------
__global__ __launch_bounds__(256, 3) void gemm_mfma_g(
    const u16* __restrict__ A, const u16* __restrict__ Wt,
    const float* __restrict__ bias, void* __restrict__ Cout,
    int M, int N, int K, int outmode, int swz)
{
  __shared__ u16 As[128 * 64];
  __shared__ u16 Bs[128 * 64];
  const int tid = threadIdx.x;
  const int wave = tid >> 6, lane = tid & 63;
  const int wr = wave >> 1, wc = wave & 1;

  int xt, yt;
  if (swz) {
    const int lin = blockIdx.y * gridDim.x + blockIdx.x;
    const int k = lin & 7, j = lin >> 3;
    const int xw = gridDim.x;
    yt = 8 * k + j / xw;
    xt = j - (j / xw) * xw;
  } else {
    xt = blockIdx.x; yt = blockIdx.y;
  }
  const int m0 = yt * 128, n0 = xt * 128;
  const int lrow = lane & 15, lk = lane >> 4;

  const int rr = lane >> 3;        // 0..7
  const int cb = (lane & 7) * 16;  // byte col 0..112

  f32x4 acc[4][4];
#pragma unroll
  for (int i = 0; i < 4; ++i)
#pragma unroll
    for (int j = 0; j < 4; ++j) {
      acc[i][j][0] = 0.f; acc[i][j][1] = 0.f; acc[i][j][2] = 0.f; acc[i][j][3] = 0.f;
    }

  for (int k0 = 0; k0 < K; k0 += 64) {
    __syncthreads();
#pragma unroll
    for (int i = 0; i < 4; ++i) {
      const int Rloc = wave * 32 + i * 8 + rr;
      const int scb = cb ^ ((Rloc & 7) << 4);
      gload16(A + (size_t)(m0 + Rloc) * K + k0 + (scb >> 1),
              &As[(wave * 32 + i * 8) * 64]);
      gload16(Wt + (size_t)(n0 + Rloc) * K + k0 + (scb >> 1),
              &Bs[(wave * 32 + i * 8) * 64]);
    }
    __syncthreads();

#pragma unroll
    for (int kk = 0; kk < 2; ++kk) {
      bf16x8 af[4], bf[4];
#pragma unroll
      for (int i = 0; i < 4; ++i) {
        const int rA = wr * 64 + i * 16 + lrow;
        af[i] = *(const bf16x8*)&As[rA * 64 + (((kk * 64 + lk * 16) ^ ((rA & 7) << 4)) >> 1)];
        const int rB = wc * 64 + i * 16 + lrow;
        bf[i] = *(const bf16x8*)&Bs[rB * 64 + (((kk * 64 + lk * 16) ^ ((rB & 7) << 4)) >> 1)];
      }
#pragma unroll
      for (int i = 0; i < 4; ++i)
#pragma unroll
        for (int j = 0; j < 4; ++j)
          acc[i][j] = __builtin_amdgcn_mfma_f32_16x16x32_bf16(af[i], bf[j], acc[i][j], 0, 0, 0);
    }
  }

#pragma unroll
  for (int j = 0; j < 4; ++j) {
    const int gcol = n0 + wc * 64 + j * 16 + lrow;
    const float bj = bias[gcol];
#pragma unroll
    for (int i = 0; i < 4; ++i) {
      const int rbase = m0 + wr * 64 + i * 16 + lk * 4;
#pragma unroll
      for (int reg = 0; reg < 4; ++reg) {
        float c = acc[i][j][reg] + bj;
        if (outmode == 1) c = gelu_f(c);
        if (outmode == 2)
          ((float*)Cout)[(size_t)(rbase + reg) * N + gcol] = c;
        else
          ((u16*)Cout)[(size_t)(rbase + reg) * N + gcol] = f2bf(c);
      }
    }
  }
}

// ---------- MFMA GEMM, guarded (small M, e.g. tags M=50) ----------
__global__ __launch_bounds__(256, 2) void gemm_mfma_k(
    const u16* __restrict__ A, const u16* __restrict__ Wt,
    const float* __restrict__ bias, void* __restrict__ Cout,
    int M, int N, int K, int outmode)
{
  __shared__ u16 As[128][40];
  __shared__ u16 Bs[128][40];
  const int tid = threadIdx.x;
  const int wave = tid >> 6, lane = tid & 63;
  const int wr = wave >> 1, wc = wave & 1;
  const int m0 = blockIdx.y * 128, n0 = blockIdx.x * 128;
  const int lrow = lane & 15, lk = lane >> 4;

  f32x4 acc[4][4];
#pragma unroll
  for (int i = 0; i < 4; ++i)
#pragma unroll
    for (int j = 0; j < 4; ++j) {
      acc[i][j][0] = 0.f; acc[i][j][1] = 0.f; acc[i][j][2] = 0.f; acc[i][j][3] = 0.f;
    }

  const int sr = tid >> 2;
  const int sk = (tid & 3) * 8;
  const bool arow_ok0 = (m0 + sr) < M;
  const bool arow_ok1 = (m0 + sr + 64) < M;

  for (int k0 = 0; k0 < K; k0 += 32) {
    __syncthreads();
    if (arow_ok0)
      *(uint4*)&As[sr][sk] = *(const uint4*)&A[(size_t)(m0 + sr) * K + k0 + sk];
    if (arow_ok1)
      *(uint4*)&As[sr + 64][sk] = *(const uint4*)&A[(size_t)(m0 + sr + 64) * K + k0 + sk];
    *(uint4*)&Bs[sr][sk] = *(const uint4*)&Wt[(size_t)(n0 + sr) * K + k0 + sk];
    *(uint4*)&Bs[sr + 64][sk] = *(const uint4*)&Wt[(size_t)(n0 + sr + 64) * K + k0 + sk];
    __syncthreads();

    bf16x8 af[4], bf[4];
#pragma unroll
    for (int i = 0; i < 4; ++i) {
      af[i] = *(const bf16x8*)&As[wr * 64 + i * 16 + lrow][lk * 8];
      bf[i] = *(const bf16x8*)&Bs[wc * 64 + i * 16 + lrow][lk * 8];
    }
#pragma unroll
    for (int i = 0; i < 4; ++i)
#pragma unroll
      for (int j = 0; j < 4; ++j)
        acc[i][j] = __builtin_amdgcn_mfma_f32_16x16x32_bf16(af[i], bf[j], acc[i][j], 0, 0, 0);
  }

#pragma unroll
  for (int j = 0; j < 4; ++j) {
    const int gcol = n0 + wc * 64 + j * 16 + lrow;
    const float bj = bias[gcol];
#pragma unroll
    for (int i = 0; i < 4; ++i) {
      const int rbase = m0 + wr * 64 + i * 16 + lk * 4;
#pragma unroll
      for (int reg = 0; reg < 4; ++reg) {
        const int grow = rbase + reg;
        if (grow >= M) continue;
        float c = acc[i][j][reg] + bj;
        if (outmode == 1) c = gelu_f(c);
        if (outmode == 2)
          ((float*)Cout)[(size_t)grow * N + gcol] = c;
        else
          ((u16*)Cout)[(size_t)grow * N + gcol] = f2bf(c);
      }
    }
  }
}

// ---------- weight transpose+convert (single) ----------
__global__ __launch_bounds__(256) void transpose_conv(
    const float* __restrict__ W, u16* __restrict__ Wt, int K, int N)
{
  __shared__ float t[32][33];
  const int kb = blockIdx.y * 32, nb = blockIdx.x * 32;
  const int x = threadIdx.x & 31;
  const int y4 = (threadIdx.x >> 5) * 4;
#pragma unroll
  for (int i = 0; i < 4; ++i)
    t[y4 + i][x] = W[(size_t)(kb + y4 + i) * N + nb + x];
  __syncthreads();
#pragma unroll
  for (int i = 0; i < 4; ++i)
    Wt[(size_t)(nb + y4 + i) * K + kb + x] = f2bf(t[x][y4 + i]);
}

// ---------- batched 1024x1024 weight transpose+convert (8 matrices) ----------
__global__ __launch_bounds__(256) void transpose_conv8(
    const float* w0, const float* w1, const float* w2, const float* w3,
    const float* w4, const float* w5, const float* w6, const float* w7,
    u16* t0, u16* t1, u16* t2, u16* t3,
    u16* t4, u16* t5, u16* t6, u16* t7)
{
  const int K = 1024, N = 1024;
  const float* W; u16* Wt;
  switch (blockIdx.z) {
    case 0: W = w0; Wt = t0; break;
    case 1: W = w1; Wt = t1; break;
    case 2: W = w2; Wt = t2; break;
    case 3: W = w3; Wt = t3; break;
    case 4: W = w4; Wt = t4; break;
    case 5: W = w5; Wt = t5; break;
    case 6: W = w6; Wt = t6; break;
    default: W = w7; Wt = t7; break;
  }
  __shared__ float t[32][33];
  const int kb = blockIdx.y * 32, nb = blockIdx.x * 32;
  const int x = threadIdx.x & 31;
  const int y4 = (threadIdx.x >> 5) * 4;
#pragma unroll
  for (int i = 0; i < 4; ++i)
    t[y4 + i][x] = W[(size_t)(kb + y4 + i) * N + nb + x];
  __syncthreads();
#pragma unroll
  for (int i = 0; i < 4; ++i)
    Wt[(size_t)(nb + y4 + i) * K + kb + x] = f2bf(t[x][y4 + i]);
}

// ---------- elementwise fp32 -> bf16 ----------
__global__ __launch_bounds__(256) void conv_bf16(
    const float* __restrict__ in, u16* __restrict__ out, int n4)
{
  const int idx = blockIdx.x * 256 + threadIdx.x;
  if (idx >= n4) return;
  const float4 v = reinterpret_cast<const float4*>(in)[idx];
  const float f[4] = {v.x, v.y, v.z, v.w};
  uint2 pk;
  pk.x = ((u32)f2bf(f[0])) | (((u32)f2bf(f[1])) << 16);
  pk.y = ((u32)f2bf(f[2])) | (((u32)f2bf(f[3])) << 16);
  reinterpret_cast<uint2*>(out)[idx] = pk;
}

// ---------- bias packing: bqkv[3072] = {sqb,skb,svb}; bckv[2048] = {ckb,cvb} ----------
__global__ __launch_bounds__(256) void pack_bias(
    const float* __restrict__ sqb, const float* __restrict__ skb,
    const float* __restrict__ svb, const float* __restrict__ ckb,
    const float* __restrict__ cvb, float* __restrict__ bqkv,
    float* __restrict__ bckv)
{
  const int t = threadIdx.x;
  switch (blockIdx.x) {
    case 0: ((float4*)bqkv)[t] = ((const float4*)sqb)[t]; break;
    case 1: ((float4*)(bqkv + 1024))[t] = ((const float4*)skb)[t]; break;
    case 2: ((float4*)(bqkv + 2048))[t] = ((const float4*)svb)[t]; break;
    case 3: ((float4*)bckv)[t] = ((const float4*)ckb)[t]; break;
    default: ((float4*)(bckv + 1024))[t] = ((const float4*)cvb)[t]; break;
  }
}

// ---------- MFMA flash self-attention (packed QKV[M][3072]) ----------
// T14 async-STAGE split + T5 setprio(1) around MFMA clusters (m191 regime:
// multiple independent blocks per CU at uncorrelated chunk phases).
__global__ __launch_bounds__(256, 4) void attn_self_mfma(
    const u16* __restrict__ QKV, u16* __restrict__ CTX,
    const int* __restrict__ rngp)
{
  const int S = 2048, H = 1024, SD = 3072;
  const float SC = 0.125f * 1.44269504f;
  const float MB = 1.44269504f;
  const int qt = blockIdx.x, h = blockIdx.y, b = blockIdx.z;
  const int range = rngp[0];
  const int tid = threadIdx.x;
  const int wave = tid >> 6, lane = tid & 63;
  const int lcol = lane & 15;
  const int lgrp = lane >> 4;

  __shared__ u16 Vt[64][72];
  __shared__ u16 Pb[4][32][72];

  const int qbase = qt * 128 + wave * 32;
  const u16* Kp = QKV + 1024;
  const u16* Vp = QKV + 2048;

  bf16x8 qf[2][2];
#pragma unroll
  for (int rf = 0; rf < 2; ++rf)
#pragma unroll
    for (int dh = 0; dh < 2; ++dh) {
      const int qrow = qbase + rf * 16 + lcol;
      qf[rf][dh] = *(const bf16x8*)&QKV[((size_t)(b * S + qrow)) * SD + h * 64 + dh * 32 + lgrp * 8];
    }

  f32x4 acc[2][4];
#pragma unroll
  for (int rf = 0; rf < 2; ++rf)
#pragma unroll
    for (int df = 0; df < 4; ++df) {
      acc[rf][df][0] = 0.f; acc[rf][df][1] = 0.f; acc[rf][df][2] = 0.f; acc[rf][df][3] = 0.f;
    }
  float lreg[2][4];
#pragma unroll
  for (int rf = 0; rf < 2; ++rf)
#pragma unroll
    for (int reg = 0; reg < 4; ++reg) lreg[rf][reg] = 0.f;

  for (int c = 0; c < 32; ++c) {
    const int kb = c * 64;
    __syncthreads();
    // --- issue V load early (global -> regs), consume after softmax ---
    const u16* vsrc = &Vp[((size_t)(b * S + kb + lane)) * SD + h * 64 + wave * 16];
    const uint4 vu0 = *(const uint4*)vsrc;
    const uint4 vu1 = *(const uint4*)(vsrc + 8);
    // --- QK^T (setprio-boosted MFMA cluster) ---
    f32x4 s[2][4];
#pragma unroll
    for (int rf = 0; rf < 2; ++rf)
#pragma unroll
      for (int cf = 0; cf < 4; ++cf) {
        s[rf][cf][0] = 0.f; s[rf][cf][1] = 0.f; s[rf][cf][2] = 0.f; s[rf][cf][3] = 0.f;
      }
    __builtin_amdgcn_s_setprio(1);
#pragma unroll
    for (int dh = 0; dh < 2; ++dh)
#pragma unroll
      for (int cf = 0; cf < 4; ++cf) {
        const int krow = kb + cf * 16 + lcol;
        const bf16x8 kf = *(const bf16x8*)&Kp[((size_t)(b * S + krow)) * SD + h * 64 + dh * 32 + lgrp * 8];
#pragma unroll
        for (int rf = 0; rf < 2; ++rf)
          s[rf][cf] = __builtin_amdgcn_mfma_f32_16x16x32_bf16(qf[rf][dh], kf, s[rf][cf], 0, 0, 0);
      }
    __builtin_amdgcn_s_setprio(0);
    // --- softmax (no-max, deferred l-reduce) ---
#pragma unroll
    for (int rf = 0; rf < 2; ++rf) {
#pragma unroll
      for (int reg = 0; reg < 4; ++reg) {
        const int qrow = qbase + rf * 16 + lgrp * 4 + reg;
#pragma unroll
        for (int cf = 0; cf < 4; ++cf) {
          const int kcol = kb + cf * 16 + lcol;
          int dd = qrow - kcol; if (dd < 0) dd = -dd;
          const float e = fast_exp2(s[rf][cf][reg] * SC + ((dd <= range) ? MB : 0.0f));
          s[rf][cf][reg] = e;
          lreg[rf][reg] += e;
        }
      }
    }
#pragma unroll
    for (int rf = 0; rf < 2; ++rf)
#pragma unroll
      for (int reg = 0; reg < 4; ++reg)
#pragma unroll
        for (int cf = 0; cf < 4; ++cf)
          Pb[wave][rf * 16 + lgrp * 4 + reg][cf * 16 + lcol] =
              (u16)(__float_as_uint(s[rf][cf][reg]) >> 16);
    // --- NOW write V to LDS (load arrived long ago) ---
    {
      u16 tmp[16];
      *(uint4*)tmp = vu0; *(uint4*)(tmp + 8) = vu1;
#pragma unroll
      for (int i = 0; i < 16; ++i) Vt[wave * 16 + i][lane] = tmp[i];
    }
    __syncthreads();
    // --- PV (setprio-boosted MFMA cluster) ---
    __builtin_amdgcn_s_setprio(1);
#pragma unroll
    for (int ks = 0; ks < 2; ++ks) {
      bf16x8 pa[2], vb[4];
#pragma unroll
      for (int rf = 0; rf < 2; ++rf)
        pa[rf] = *(const bf16x8*)&Pb[wave][rf * 16 + lcol][ks * 32 + lgrp * 8];
#pragma unroll
      for (int df = 0; df < 4; ++df)
        vb[df] = *(const bf16x8*)&Vt[df * 16 + lcol][ks * 32 + lgrp * 8];
#pragma unroll
      for (int rf = 0; rf < 2; ++rf)
#pragma unroll
        for (int df = 0; df < 4; ++df)
          acc[rf][df] = __builtin_amdgcn_mfma_f32_16x16x32_bf16(pa[rf], vb[df], acc[rf][df], 0, 0, 0);
    }
    __builtin_amdgcn_s_setprio(0);
  }
#pragma unroll
  for (int rf = 0; rf < 2; ++rf)
#pragma unroll
    for (int reg = 0; reg < 4; ++reg) {
      float l = lreg[rf][reg];
      l += __shfl_xor(l, 1);
      l += __shfl_xor(l, 2);
      l += __shfl_xor(l, 4);
      l += __shfl_xor(l, 8);
      lreg[rf][reg] = l;
    }
#pragma unroll
  for (int rf = 0; rf < 2; ++rf)
#pragma unroll
    for (int reg = 0; reg < 4; ++reg) {
      const int qrow = qbase + rf * 16 + lgrp * 4 + reg;
      const float inv = 1.f / lreg[rf][reg];
#pragma unroll
      for (int df = 0; df < 4; ++df)
        CTX[((size_t)(b * S + qrow)) * H + h * 64 + df * 16 + lcol] =
            f2bf(acc[rf][df][reg] * inv);
    }
}

// ---------- MFMA cross-attention: packed KV[50][2048] (K at 0, V at +1024) ----------
__global__ __launch_bounds__(256, 4) void attn_cross_mfma(
    const u16* __restrict__ Q, const u16* __restrict__ KV,
    u16* __restrict__ CTX)
{
  const int S = 2048, H = 1024, T = 50, KD = 2048;
  const float SC = 0.125f * 1.44269504f;
  const int qt = blockIdx.x, h = blockIdx.y, b = blockIdx.z;
  const int tid = threadIdx.x;
  const int wave = tid >> 6, lane = tid & 63;
  const int lcol = lane & 15;
  const int lgrp = lane >> 4;

  __shared__ u16 Vt[64][72];
  __shared__ u16 Pb[4][32][72];

  const int qbase = qt * 128 + wave * 32;

  bf16x8 qf[2][2];
#pragma unroll
  for (int rf = 0; rf < 2; ++rf)
#pragma unroll
    for (int dh = 0; dh < 2; ++dh) {
      const int qrow = qbase + rf * 16 + lcol;
      qf[rf][dh] = *(const bf16x8*)&Q[((size_t)(b * S + qrow)) * H + h * 64 + dh * 32 + lgrp * 8];
    }

  {
    u16 tmp[16];
    if (lane < T) {
      const u16* vsrc = &KV[(size_t)lane * KD + 1024 + h * 64 + wave * 16];
      *(uint4*)tmp = *(const uint4*)vsrc;
      *(uint4*)(tmp + 8) = *(const uint4*)(vsrc + 8);
    } else {
#pragma unroll
      for (int i = 0; i < 16; ++i) tmp[i] = 0;
    }
#pragma unroll
    for (int i = 0; i < 16; ++i) Vt[wave * 16 + i][lane] = tmp[i];
  }

  f32x4 s[2][4];
#pragma unroll
  for (int rf = 0; rf < 2; ++rf)
#pragma unroll
    for (int cf = 0; cf < 4; ++cf) {
      s[rf][cf][0] = 0.f; s[rf][cf][1] = 0.f; s[rf][cf][2] = 0.f; s[rf][cf][3] = 0.f;
    }
  __builtin_amdgcn_s_setprio(1);
#pragma unroll
  for (int dh = 0; dh < 2; ++dh)
#pragma unroll
    for (int cf = 0; cf < 4; ++cf) {
      const int krow = cf * 16 + lcol;
      const bf16x8 kf = *(const bf16x8*)&KV[(size_t)krow * KD + h * 64 + dh * 32 + lgrp * 8];
#pragma unroll
      for (int rf = 0; rf < 2; ++rf)
        s[rf][cf] = __builtin_amdgcn_mfma_f32_16x16x32_bf16(qf[rf][dh], kf, s[rf][cf], 0, 0, 0);
    }
  __builtin_amdgcn_s_setprio(0);

  float inv_l[2][4];
#pragma unroll
  for (int rf = 0; rf < 2; ++rf) {
#pragma unroll
    for (int reg = 0; reg < 4; ++reg) {
      float rmax = -1e30f;
#pragma unroll
      for (int cf = 0; cf < 4; ++cf) {
        const int kcol = cf * 16 + lcol;
        const float v = (kcol < T) ? s[rf][cf][reg] * SC : -1e30f;
        s[rf][cf][reg] = v;
        rmax = fmaxf(rmax, v);
      }
      rmax = fmaxf(rmax, __shfl_xor(rmax, 1));
      rmax = fmaxf(rmax, __shfl_xor(rmax, 2));
      rmax = fmaxf(rmax, __shfl_xor(rmax, 4));
      rmax = fmaxf(rmax, __shfl_xor(rmax, 8));
      float rsum = 0.f;
#pragma unroll
      for (int cf = 0; cf < 4; ++cf) {
        const float e = fast_exp2(s[rf][cf][reg] - rmax);
        s[rf][cf][reg] = e;
        rsum += e;
      }
      rsum += __shfl_xor(rsum, 1);
      rsum += __shfl_xor(rsum, 2);
      rsum += __shfl_xor(rsum, 4);
      rsum += __shfl_xor(rsum, 8);
      inv_l[rf][reg] = 1.f / rsum;
    }
  }
#pragma unroll
  for (int rf = 0; rf < 2; ++rf)
#pragma unroll
    for (int reg = 0; reg < 4; ++reg)
#pragma unroll
      for (int cf = 0; cf < 4; ++cf)
        Pb[wave][rf * 16 + lgrp * 4 + reg][cf * 16 + lcol] = f2bf(s[rf][cf][reg]);
  __syncthreads();

  f32x4 acc[2][4];
#pragma unroll
  for (int rf = 0; rf < 2; ++rf)
#pragma unroll
    for (int df = 0; df < 4; ++df) {
      acc[rf][df][0] = 0.f; acc[rf][df][1] = 0.f; acc[rf][df][2] = 0.f; acc[rf][df][3] = 0.f;
    }
  __builtin_amdgcn_s_setprio(1);
#pragma unroll
  for (int ks = 0; ks < 2; ++ks) {
    bf16x8 pa[2], vb[4];
#pragma unroll
    for (int rf = 0; rf < 2; ++rf)
      pa[rf] = *(const bf16x8*)&Pb[wave][rf * 16 + lcol][ks * 32 + lgrp * 8];
#pragma unroll
    for (int df = 0; df < 4; ++df)
      vb[df] = *(const bf16x8*)&Vt[df * 16 + lcol][ks * 32 + lgrp * 8];
#pragma unroll
    for (int rf = 0; rf < 2; ++rf)
#pragma unroll
      for (int df = 0; df < 4; ++df)
        acc[rf][df] = __builtin_amdgcn_mfma_f32_16x16x32_bf16(pa[rf], vb[df], acc[rf][df], 0, 0, 0);
  }
  __builtin_amdgcn_s_setprio(0);
#pragma unroll
  for (int rf = 0; rf < 2; ++rf)
#pragma unroll
    for (int reg = 0; reg < 4; ++reg) {
      const int qrow = qbase + rf * 16 + lgrp * 4 + reg;
      const float inv = inv_l[rf][reg];
#pragma unroll
      for (int df = 0; df < 4; ++df)
        CTX[((size_t)(b * S + qrow)) * H + h * 64 + df * 16 + lcol] =
            f2bf(acc[rf][df][reg] * inv);
    }
}

// ---------- residual + LayerNorm ----------
template<bool CF32, bool RF32, bool OF32>
__global__ __launch_bounds__(256) void ln_res(
    const void* __restrict__ C, const void* __restrict__ Res,
    const float* __restrict__ G, const float* __restrict__ Bb,
    void* __restrict__ Out)
{
  const int H = 1024;
  const int row = blockIdx.x;
  const int tid = threadIdx.x;
  float x[4];
  {
    float c4[4], r4[4];
    if (CF32) {
      const float4 c = reinterpret_cast<const float4*>((const float*)C + (size_t)row * H)[tid];
      c4[0] = c.x; c4[1] = c.y; c4[2] = c.z; c4[3] = c.w;
    } else {
      const uint2 cu = reinterpret_cast<const uint2*>((const u16*)C + (size_t)row * H)[tid];
      c4[0] = __uint_as_float(cu.x << 16); c4[1] = __uint_as_float(cu.x & 0xffff0000u);
      c4[2] = __uint_as_float(cu.y << 16); c4[3] = __uint_as_float(cu.y & 0xffff0000u);
    }
    if (RF32) {
      const float4 rr = reinterpret_cast<const float4*>((const float*)Res + (size_t)row * H)[tid];
      r4[0] = rr.x; r4[1] = rr.y; r4[2] = rr.z; r4[3] = rr.w;
    } else {
      const uint2 ru = reinterpret_cast<const uint2*>((const u16*)Res + (size_t)row * H)[tid];
      r4[0] = __uint_as_float(ru.x << 16); r4[1] = __uint_as_float(ru.x & 0xffff0000u);
      r4[2] = __uint_as_float(ru.y << 16); r4[3] = __uint_as_float(ru.y & 0xffff0000u);
    }
#pragma unroll
    for (int i = 0; i < 4; ++i) x[i] = c4[i] + r4[i];
  }
  float s = x[0] + x[1] + x[2] + x[3];
  float q = x[0] * x[0] + x[1] * x[1] + x[2] * x[2] + x[3] * x[3];
#pragma unroll
  for (int off = 1; off < 64; off <<= 1) {
    s += __shfl_xor(s, off);
    q += __shfl_xor(q, off);
  }
  __shared__ float sb[4][2];
  const int wid = tid >> 6;
  if ((tid & 63) == 0) { sb[wid][0] = s; sb[wid][1] = q; }
  __syncthreads();
  s = sb[0][0] + sb[1][0] + sb[2][0] + sb[3][0];
  q = sb[0][1] + sb[1][1] + sb[2][1] + sb[3][1];
  const float mean = s * (1.f / 1024.f);
  const float var = q * (1.f / 1024.f) - mean * mean;
  const float rstd = rsqrtf(fmaxf(var, 0.f) + 1e-12f);
  const float4 g4 = reinterpret_cast<const float4*>(G)[tid];
  const float4 b4 = reinterpret_cast<const float4*>(Bb)[tid];
  float o[4];
  o[0] = (x[0] - mean) * rstd * g4.x + b4.x;
  o[1] = (x[1] - mean) * rstd * g4.y + b4.y;
  o[2] = (x[2] - mean) * rstd * g4.z + b4.z;
  o[3] = (x[3] - mean) * rstd * g4.w + b4.w;
  if (OF32) {
    reinterpret_cast<float4*>((float*)Out + (size_t)row * H)[tid] =
        make_float4(o[0], o[1], o[2], o[3]);
  } else {
    uint2 pk;
    pk.x = ((u32)f2bf(o[0])) | (((u32)f2bf(o[1])) << 16);
    pk.y = ((u32)f2bf(o[2])) | (((u32)f2bf(o[3])) << 16);
    reinterpret_cast<uint2*>((u16*)Out + (size_t)row * H)[tid] = pk;
  }
}

// ---------- tag gather ----------
__global__ void gather_tags(const float* __restrict__ emb, const int* __restrict__ ids,
                            u16* __restrict__ tags)
{
  const int t = blockIdx.x;
  const int id = ids[t];
  const float4* src = reinterpret_cast<const float4*>(emb + (size_t)id * 1024);
  const float4 a = src[threadIdx.x * 2], b = src[threadIdx.x * 2 + 1];
  const float f[8] = {a.x, a.y, a.z, a.w, b.x, b.y, b.z, b.w};
  reinterpret_cast<uint4*>(tags + (size_t)t * 1024)[threadIdx.x] = pack8(f);
}

// ---------- host ----------
extern "C" void kernel_launch(void* const* d_in, const int* in_sizes, int n_in,
                              void* d_out, int out_size, void* d_ws, size_t ws_size,
                              hipStream_t stream)
{
  const int B = 4, S = 2048, H = 1024, FFN = 4096, T = 50;
  const int M = B * S;

  const bool dict_order = (in_sizes[10] == H * H);
  int i_cqw, i_cqb, i_ckw, i_ckb, i_cvw, i_cvb, i_cow, i_cob;
  int i_slng, i_slnb, i_clng, i_clnb, i_olng, i_olnb;
  int i_iw, i_ib, i_ow, i_ob;
  if (dict_order) {
    i_cqw = 10; i_cqb = 11; i_ckw = 12; i_ckb = 13; i_cvw = 14; i_cvb = 15; i_cow = 16; i_cob = 17;
    i_slng = 18; i_slnb = 19; i_clng = 20; i_clnb = 21; i_olng = 22; i_olnb = 23;
    i_iw = 24; i_ib = 25; i_ow = 26; i_ob = 27;
  } else {
    i_slng = 10; i_slnb = 11;
    i_cqw = 12; i_cqb = 13; i_ckw = 14; i_ckb = 15; i_cvw = 16; i_cvb = 17; i_cow = 18; i_cob = 19;
    i_clng = 20; i_clnb = 21;
    i_iw = 22; i_ib = 23; i_ow = 24; i_ob = 25; i_olng = 26; i_olnb = 27;
  }
  const float* X    = (const float*)d_in[0];
  const float* EMB  = (const float*)d_in[1];
  const float* SQW  = (const float*)d_in[2];
  const float* SQB  = (const float*)d_in[3];
  const float* SKW  = (const float*)d_in[4];
  const float* SKB  = (const float*)d_in[5];
  const float* SVW  = (const float*)d_in[6];
  const float* SVB  = (const float*)d_in[7];
  const float* SOW  = (const float*)d_in[8];
  const float* SOB  = (const float*)d_in[9];
  const float* CQW  = (const float*)d_in[i_cqw];
  const float* CQB  = (const float*)d_in[i_cqb];
  const float* CKW  = (const float*)d_in[i_ckw];
  const float* CKB  = (const float*)d_in[i_ckb];
  const float* CVW  = (const float*)d_in[i_cvw];
  const float* CVB  = (const float*)d_in[i_cvb];
  const float* COW  = (const float*)d_in[i_cow];
  const float* COB  = (const float*)d_in[i_cob];
  const float* SLNG = (const float*)d_in[i_slng];
  const float* SLNB = (const float*)d_in[i_slnb];
  const float* CLNG = (const float*)d_in[i_clng];
  const float* CLNB = (const float*)d_in[i_clnb];
  const float* OLNG = (const float*)d_in[i_olng];
  const float* OLNB = (const float*)d_in[i_olnb];
  const float* IW   = (const float*)d_in[i_iw];
  const float* IB   = (const float*)d_in[i_ib];
  const float* OW   = (const float*)d_in[i_ow];
  const float* OB   = (const float*)d_in[i_ob];
  const int* IDS  = (const int*)d_in[28];
  const int* RNG  = (const int*)d_in[29];

  char* ws = (char*)d_ws;
  u16* tags  = (u16*)(ws);                       // 100 KB
  u16* kvtag = (u16*)(ws + (1 << 17));           // 200 KB  [50][2048]
  float* bqkv = (float*)(ws + (3 << 17));        // 12 KB
  float* bckv = (float*)(ws + (3 << 17) + 16384);// 8 KB
  char* wreg = ws + (4 << 17);
  const size_t WHH = (size_t)H * H * 2;
  u16* wsq = (u16*)(wreg);            // wsq,wsk,wsv contiguous -> QKV weight [3072][1024]
  u16* wsk = (u16*)(wreg + WHH);
  u16* wsv = (u16*)(wreg + 2 * WHH);
  u16* wso = (u16*)(wreg + 3 * WHH);
  u16* wcq = (u16*)(wreg + 4 * WHH);
  u16* wck = (u16*)(wreg + 5 * WHH);  // wck,wcv contiguous -> KV weight [2048][1024]
  u16* wcv = (u16*)(wreg + 6 * WHH);
  u16* wco = (u16*)(wreg + 7 * WHH);
  u16* wit = (u16*)(wreg + 8 * WHH);
  u16* wot = (u16*)(wreg + 8 * WHH + (size_t)H * FFN * 2);
  char* slots = wreg + 8 * WHH + 2 * (size_t)H * FFN * 2;
  const size_t SZ = (size_t)M * H * 2;
  u16* s0 = (u16*)(slots);
  u16* s1 = (u16*)(slots + SZ);
  u16* s2 = (u16*)(slots + 2 * SZ);
  u16* s3 = (u16*)(slots + 3 * SZ);
  u16* s4 = (u16*)(slots + 4 * SZ);
  u16* qkv = s0;                      // packed [M][3072] spans s0..s2
  u16* inter = s0;                    // [M][FFN] spans s0..s3
  float* outp = (float*)d_out;

  const dim3 blk(256);
  const dim3 gsq(H / 128, M / 128);

  conv_bf16<<<dim3((M * H / 4 + 255) / 256), blk, 0, stream>>>(X, s4, M * H / 4);
  transpose_conv8<<<dim3(H / 32, H / 32, 8), blk, 0, stream>>>(
      SQW, SKW, SVW, SOW, CQW, CKW, CVW, COW,
      wsq, wsk, wsv, wso, wcq, wck, wcv, wco);
  transpose_conv<<<dim3(FFN / 32, H / 32), blk, 0, stream>>>(IW, wit, H, FFN);
  transpose_conv<<<dim3(H / 32, FFN / 32), blk, 0, stream>>>(OW, wot, FFN, H);
  pack_bias<<<dim3(5), blk, 0, stream>>>(SQB, SKB, SVB, CKB, CVB, bqkv, bckv);

  // --- self-attention block ---
  gemm_mfma_g<<<dim3(3 * H / 128, M / 128), blk, 0, stream>>>(
      s4, wsq, bqkv, qkv, M, 3 * H, H, 0, 0);                             // fused QKV
  attn_self_mfma<<<dim3(S / 128, 16, B), blk, 0, stream>>>(qkv, s3, RNG);
  gemm_mfma_g<<<gsq, blk, 0, stream>>>(s3, wso, SOB, s0, M, H, H, 0, 1);  // so_out
  ln_res<false, false, false><<<dim3(M), blk, 0, stream>>>(s0, s4, SLNG, SLNB, s3);  // Res = bf16(X)

  // --- cross-attention block ---
  gather_tags<<<dim3(T), dim3(128), 0, stream>>>(EMB, IDS, tags);
  gemm_mfma_k<<<dim3(2 * H / 128, 1), blk, 0, stream>>>(tags, wck, bckv, kvtag, T, 2 * H, H, 0);  // fused tag K/V
  gemm_mfma_g<<<gsq, blk, 0, stream>>>(s3, wcq, CQB, s0, M, H, H, 0, 1);  // cq
  attn_cross_mfma<<<dim3(S / 128, 16, B), blk, 0, stream>>>(s0, kvtag, s1);
  gemm_mfma_g<<<gsq, blk, 0, stream>>>(s1, wco, COB, s2, M, H, H, 0, 1);  // co_out
  ln_res<false, false, false><<<dim3(M), blk, 0, stream>>>(s2, s3, CLNG, CLNB, s4);

  // --- FFN block ---
  gemm_mfma_g<<<dim3(FFN / 128, M / 128), blk, 0, stream>>>(s4, wit, IB, inter, M, FFN, H, 1, 0);
  gemm_mfma_g<<<gsq, blk, 0, stream>>>(inter, wot, OB, outp, M, H, FFN, 2, 0);
  ln_res<true, false, true><<<dim3(M), blk, 0, stream>>>(outp, s4, OLNG, OLNB, outp);
}